// Round 1
// baseline (476.320 us; speedup 1.0000x reference)
//
#include <hip/hip_runtime.h>
#include <math.h>

#define C_DIM 1024
#define B_SZ 2
#define N_SEQ 2048
#define M_ROWS (B_SZ * N_SEQ)   // 4096
#define H_NUM 16
#define D_HEAD 64

__device__ __forceinline__ float elu1(float v) {
    return v > 0.f ? v + 1.f : expf(v);
}

// ---------------------------------------------------------------------------
// GEMM: dst[m, col] = act( X[m,:] . W[col,:] ) (+bias)
// X: [M_ROWS, 1024] row-major. Weights row-major [out, 1024] (torch Linear).
// Output col space = gridDim.y*128 wide; cols < 1024 use W0, cols >= 1024 use
// W1 (rows offset by col-1024). act applied iff col < act_cols.
// 128x128 tile, BK=16, 256 threads, 8x8 per thread (2x2 blocks of 4x4).
// ---------------------------------------------------------------------------
__global__ __launch_bounds__(256)
void gemm_xwt_kernel(const float* __restrict__ X,
                     const float* __restrict__ W0,
                     const float* __restrict__ W1,
                     const float* __restrict__ bias,
                     float* __restrict__ dst,
                     int ldd, int act_cols)
{
    __shared__ float As[16][132];
    __shared__ float Bs[16][132];

    const int m0 = blockIdx.x * 128;
    const int j0 = blockIdx.y * 128;
    const float* W = (j0 < C_DIM) ? (W0 + (size_t)j0 * C_DIM)
                                  : (W1 + (size_t)(j0 - C_DIM) * C_DIM);
    const int t  = threadIdx.x;
    const int lr = t >> 1;            // 0..127 (load row within tile)
    const int lc = (t & 1) << 3;      // 0 or 8 (load col offset)
    const int ty = t >> 4;            // 0..15
    const int tx = t & 15;            // 0..15

    float acc[2][2][4][4];
    #pragma unroll
    for (int a = 0; a < 2; ++a)
        #pragma unroll
        for (int b = 0; b < 2; ++b)
            #pragma unroll
            for (int i = 0; i < 4; ++i)
                #pragma unroll
                for (int j = 0; j < 4; ++j)
                    acc[a][b][i][j] = 0.f;

    const float* xp = X + (size_t)(m0 + lr) * C_DIM + lc;
    const float* wp = W + (size_t)lr * C_DIM + lc;

    for (int kk = 0; kk < C_DIM; kk += 16) {
        const float4 xa = *(const float4*)(xp + kk);
        const float4 xb = *(const float4*)(xp + kk + 4);
        const float4 wa = *(const float4*)(wp + kk);
        const float4 wb = *(const float4*)(wp + kk + 4);
        __syncthreads();
        As[lc+0][lr] = xa.x; As[lc+1][lr] = xa.y; As[lc+2][lr] = xa.z; As[lc+3][lr] = xa.w;
        As[lc+4][lr] = xb.x; As[lc+5][lr] = xb.y; As[lc+6][lr] = xb.z; As[lc+7][lr] = xb.w;
        Bs[lc+0][lr] = wa.x; Bs[lc+1][lr] = wa.y; Bs[lc+2][lr] = wa.z; Bs[lc+3][lr] = wa.w;
        Bs[lc+4][lr] = wb.x; Bs[lc+5][lr] = wb.y; Bs[lc+6][lr] = wb.z; Bs[lc+7][lr] = wb.w;
        __syncthreads();
        #pragma unroll
        for (int k = 0; k < 16; ++k) {
            const float4 a0 = *(const float4*)&As[k][ty * 4];
            const float4 a1 = *(const float4*)&As[k][64 + ty * 4];
            const float4 b0 = *(const float4*)&Bs[k][tx * 4];
            const float4 b1 = *(const float4*)&Bs[k][64 + tx * 4];
            const float av[2][4] = {{a0.x, a0.y, a0.z, a0.w}, {a1.x, a1.y, a1.z, a1.w}};
            const float bv[2][4] = {{b0.x, b0.y, b0.z, b0.w}, {b1.x, b1.y, b1.z, b1.w}};
            #pragma unroll
            for (int ib = 0; ib < 2; ++ib)
                #pragma unroll
                for (int jb = 0; jb < 2; ++jb)
                    #pragma unroll
                    for (int i = 0; i < 4; ++i)
                        #pragma unroll
                        for (int j = 0; j < 4; ++j)
                            acc[ib][jb][i][j] += av[ib][i] * bv[jb][j];
        }
    }

    const bool act = (j0 < act_cols);
    #pragma unroll
    for (int ib = 0; ib < 2; ++ib) {
        #pragma unroll
        for (int i = 0; i < 4; ++i) {
            const int row = m0 + ib * 64 + ty * 4 + i;
            #pragma unroll
            for (int jb = 0; jb < 2; ++jb) {
                const int col = j0 + jb * 64 + tx * 4;
                float4 o;
                o.x = acc[ib][jb][i][0];
                o.y = acc[ib][jb][i][1];
                o.z = acc[ib][jb][i][2];
                o.w = acc[ib][jb][i][3];
                if (bias) {
                    o.x += bias[col + 0]; o.y += bias[col + 1];
                    o.z += bias[col + 2]; o.w += bias[col + 3];
                }
                if (act) {
                    o.x = elu1(o.x); o.y = elu1(o.y);
                    o.z = elu1(o.z); o.w = elu1(o.w);
                }
                *(float4*)(dst + (size_t)row * ldd + col) = o;
            }
        }
    }
}

// ---------------------------------------------------------------------------
// Partial KV = K_feat^T V and ksum = sum_n k_feat, per (b,h), split 16-way
// over N (deterministic reduction later). QKV layout [4096, 3072]:
// cols [0,1024)=Q, [1024,2048)=K, [2048,3072)=V.
// KVp layout: [split s][bh][4160]  (4096 KV + 64 ksum)
// ---------------------------------------------------------------------------
__global__ __launch_bounds__(256)
void kv_partial_kernel(const float* __restrict__ QKV, float* __restrict__ KVp)
{
    const int bh = blockIdx.x;   // 0..31
    const int s  = blockIdx.y;   // 0..15
    const int b  = bh >> 4;
    const int h  = bh & 15;
    const int t  = threadIdx.x;

    __shared__ float ks[4][68];
    __shared__ float vs[4][68];

    const int d0 = (t >> 4) * 4;      // 0..60
    const int e0 = (t & 15) * 4;      // 0..60

    float acc[4][4];
    #pragma unroll
    for (int i = 0; i < 4; ++i)
        #pragma unroll
        for (int j = 0; j < 4; ++j) acc[i][j] = 0.f;
    float acc_ks[4] = {0.f, 0.f, 0.f, 0.f};

    const int lrow = t >> 6;     // 0..3
    const int lcol = t & 63;     // 0..63
    const size_t kbase = (size_t)b * N_SEQ * 3072 + 1024 + h * 64 + lcol;
    const size_t vbase = (size_t)b * N_SEQ * 3072 + 2048 + h * 64 + lcol;

    for (int it = 0; it < 32; ++it) {
        const int n0 = s * 128 + it * 4;
        const float kval = QKV[kbase + (size_t)(n0 + lrow) * 3072];
        const float vval = QKV[vbase + (size_t)(n0 + lrow) * 3072];
        __syncthreads();
        ks[lrow][lcol] = kval;
        vs[lrow][lcol] = vval;
        __syncthreads();
        #pragma unroll
        for (int r = 0; r < 4; ++r) {
            const float4 k4 = *(const float4*)&ks[r][d0];
            const float4 v4 = *(const float4*)&vs[r][e0];
            const float ka[4] = {k4.x, k4.y, k4.z, k4.w};
            const float va[4] = {v4.x, v4.y, v4.z, v4.w};
            #pragma unroll
            for (int i = 0; i < 4; ++i)
                #pragma unroll
                for (int j = 0; j < 4; ++j)
                    acc[i][j] += ka[i] * va[j];
            if (e0 == 0) {
                #pragma unroll
                for (int i = 0; i < 4; ++i) acc_ks[i] += ka[i];
            }
        }
    }

    float* outp = KVp + ((size_t)s * 32 + bh) * 4160;
    #pragma unroll
    for (int i = 0; i < 4; ++i) {
        float4 o; o.x = acc[i][0]; o.y = acc[i][1]; o.z = acc[i][2]; o.w = acc[i][3];
        *(float4*)(outp + (d0 + i) * 64 + e0) = o;
    }
    if (e0 == 0) {
        #pragma unroll
        for (int i = 0; i < 4; ++i) outp[4096 + d0 + i] = acc_ks[i];
    }
}

// Deterministic reduce of the 16 partials: KVf[idx] = sum_s KVp[s][idx]
__global__ __launch_bounds__(256)
void kv_reduce_kernel(const float* __restrict__ KVp, float* __restrict__ KVf)
{
    const int idx = blockIdx.x * 256 + threadIdx.x;   // < 32*4160 = 133120
    if (idx < 32 * 4160) {
        float s = 0.f;
        #pragma unroll
        for (int i = 0; i < 16; ++i) s += KVp[(size_t)i * (32 * 4160) + idx];
        KVf[idx] = s;
    }
}

// ---------------------------------------------------------------------------
// O1[b*N+n, h*64+e] = Z * sum_d q[n,d] * KV[d,e],  Z = 1/(q . ksum + 1e-6)
// One block: 16 q-rows of one (b,h). 256 threads: thread = (row r, e-quad).
// ---------------------------------------------------------------------------
__global__ __launch_bounds__(256)
void attn_apply_kernel(const float* __restrict__ QKV, const float* __restrict__ KVf,
                       float* __restrict__ O1)
{
    const int bh = blockIdx.x;
    const int b = bh >> 4, h = bh & 15;
    const int n0 = blockIdx.y * 16;
    const int t = threadIdx.x;
    const int r  = t >> 4;           // 0..15
    const int e0 = (t & 15) * 4;     // 0..60

    __shared__ float kvs[64][68];
    __shared__ float qs[16][68];
    __shared__ float ksums[64];

    const float* kvb = KVf + (size_t)bh * 4160;
    for (int i = t; i < 4096; i += 256)
        kvs[i >> 6][i & 63] = kvb[i];
    if (t < 64) ksums[t] = kvb[4096 + t];
    {
        const int rr = t >> 4, cc = (t & 15) * 4;
        *(float4*)&qs[rr][cc] =
            *(const float4*)&QKV[(size_t)(b * N_SEQ + n0 + rr) * 3072 + h * 64 + cc];
    }
    __syncthreads();

    float4 acc = {0.f, 0.f, 0.f, 0.f};
    float accz = 0.f;
    #pragma unroll
    for (int d = 0; d < 64; ++d) {
        const float qv = qs[r][d];
        const float4 kvv = *(const float4*)&kvs[d][e0];
        acc.x += qv * kvv.x; acc.y += qv * kvv.y;
        acc.z += qv * kvv.z; acc.w += qv * kvv.w;
        accz += qv * ksums[d];
    }
    const float Z = 1.f / (accz + 1e-6f);
    acc.x *= Z; acc.y *= Z; acc.z *= Z; acc.w *= Z;
    *(float4*)&O1[(size_t)(b * N_SEQ + n0 + r) * C_DIM + h * 64 + e0] = acc;
}

extern "C" void kernel_launch(void* const* d_in, const int* in_sizes, int n_in,
                              void* d_out, int out_size, void* d_ws, size_t ws_size,
                              hipStream_t stream)
{
    const float* x   = (const float*)d_in[0];
    const float* Wq  = (const float*)d_in[1];
    const float* Wkv = (const float*)d_in[2];
    const float* Wo  = (const float*)d_in[3];
    const float* bo  = (const float*)d_in[4];
    float* out = (float*)d_out;

    float* ws  = (float*)d_ws;
    float* QKV = ws;                              // 4096*3072 floats
    float* O1  = QKV + (size_t)M_ROWS * 3072;     // 4096*1024
    float* KVp = O1  + (size_t)M_ROWS * 1024;     // 16*32*4160
    float* KVf = KVp + (size_t)16 * 32 * 4160;    // 32*4160

    // 1. fused q/k/v projections + elu+1 on q,k
    gemm_xwt_kernel<<<dim3(M_ROWS / 128, 3072 / 128), 256, 0, stream>>>(
        x, Wq, Wkv, nullptr, QKV, 3072, 2048);

    // 2. per-(b,h) partial KV + ksum (16-way N split, deterministic)
    kv_partial_kernel<<<dim3(32, 16), 256, 0, stream>>>(QKV, KVp);

    // 3. reduce partials
    kv_reduce_kernel<<<dim3((32 * 4160 + 255) / 256), 256, 0, stream>>>(KVp, KVf);

    // 4. apply: O1 = Z * (q @ KV)
    attn_apply_kernel<<<dim3(32, 128), 256, 0, stream>>>(QKV, KVf, O1);

    // 5. final projection + bias
    gemm_xwt_kernel<<<dim3(M_ROWS / 128, 1024 / 128), 256, 0, stream>>>(
        O1, Wo, Wo, bo, out, 1024, 0);
}

// Round 2
// 220.263 us; speedup vs baseline: 2.1625x; 2.1625x over previous
//
#include <hip/hip_runtime.h>
#include <math.h>

#define C_DIM 1024
#define B_SZ 2
#define N_SEQ 2048
#define M_ROWS (B_SZ * N_SEQ)   // 4096
#define KDIM 1024
#define PAD 36                  // ushorts per LDS row: 32 data + 4 pad (72 B, bank stride 18)

typedef float  f32x4   __attribute__((ext_vector_type(4)));
typedef short  bf16x8  __attribute__((ext_vector_type(8)));
typedef short  short4v __attribute__((ext_vector_type(4)));
typedef short  short8v __attribute__((ext_vector_type(8)));

__device__ __forceinline__ float elu1(float v) {
    return v > 0.f ? v + 1.f : expf(v);
}

__device__ __forceinline__ ushort f2bf(float f) {
    union { float f; unsigned u; } x; x.f = f;
    unsigned r = (x.u + 0x7fffu + ((x.u >> 16) & 1u)) >> 16;  // RNE
    return (ushort)r;
}
__device__ __forceinline__ float bf2f(ushort b) {
    union { unsigned u; float f; } x; x.u = ((unsigned)b) << 16;
    return x.f;
}

__device__ __forceinline__ bf16x8 ldsfrag(const ushort* p) {
    short4v a = *(const short4v*)p;
    short4v b = *(const short4v*)(p + 4);
    return __builtin_shufflevector(a, b, 0, 1, 2, 3, 4, 5, 6, 7);
}

// ---------------------------------------------------------------------------
// fp32 -> bf16 hi/lo split, 8 elems/thread
// ---------------------------------------------------------------------------
__global__ __launch_bounds__(256)
void split_hilo_kernel(const float* __restrict__ in, ushort* __restrict__ hi,
                       ushort* __restrict__ lo, int n8)
{
    const int i = blockIdx.x * 256 + threadIdx.x;
    if (i >= n8) return;
    const float4 a = ((const float4*)in)[i * 2];
    const float4 b = ((const float4*)in)[i * 2 + 1];
    const float v[8] = {a.x, a.y, a.z, a.w, b.x, b.y, b.z, b.w};
    ushort hv[8], lv[8];
    #pragma unroll
    for (int j = 0; j < 8; ++j) {
        hv[j] = f2bf(v[j]);
        lv[j] = f2bf(v[j] - bf2f(hv[j]));
    }
    short8v H = {(short)hv[0],(short)hv[1],(short)hv[2],(short)hv[3],
                 (short)hv[4],(short)hv[5],(short)hv[6],(short)hv[7]};
    short8v L = {(short)lv[0],(short)lv[1],(short)lv[2],(short)lv[3],
                 (short)lv[4],(short)lv[5],(short)lv[6],(short)lv[7]};
    *(short8v*)&hi[(size_t)i * 8] = H;
    *(short8v*)&lo[(size_t)i * 8] = L;
}

// ---------------------------------------------------------------------------
// Split-bf16 MFMA GEMM: dst[m,n] = act( A[m,:] . B[n,:] + bias[n] )
// A,B given as bf16 hi/lo pairs, K = 1024, row-major with row stride KDIM.
// 3-term split: Ah*Bh + Ah*Bl + Al*Bh  (lo*lo dropped, ~2^-16 rel).
// 128x128 tile, BK=32, 256 threads = 4 waves (2x2), 4x4 16x16 frags/wave.
// ---------------------------------------------------------------------------
__global__ __launch_bounds__(256)
void gemm_mfma_kernel(const ushort* __restrict__ Ahi, const ushort* __restrict__ Alo,
                      const ushort* __restrict__ Bhi, const ushort* __restrict__ Blo,
                      const float* __restrict__ bias, float* __restrict__ dst,
                      int ldd, int act_cols)
{
    __shared__ ushort sAh[128 * PAD];
    __shared__ ushort sAl[128 * PAD];
    __shared__ ushort sBh[128 * PAD];
    __shared__ ushort sBl[128 * PAD];

    const int m0 = blockIdx.x * 128;
    const int j0 = blockIdx.y * 128;
    const int t = threadIdx.x;
    const int lane = t & 63;
    const int w = t >> 6;
    const int wr = w >> 1, wc = w & 1;      // wave 2x2 grid, 64x64 each

    // staging: thread -> (row lr, k-half)
    const int lr = t >> 1;                  // 0..127
    const int half = t & 1;                 // 16-elem half of BK=32
    const ushort* gAh = Ahi + (size_t)(m0 + lr) * KDIM + half * 16;
    const ushort* gAl = Alo + (size_t)(m0 + lr) * KDIM + half * 16;
    const ushort* gBh = Bhi + (size_t)(j0 + lr) * KDIM + half * 16;
    const ushort* gBl = Blo + (size_t)(j0 + lr) * KDIM + half * 16;
    const int lws = lr * PAD + half * 16;   // LDS element offset

    const int frow = lane & 15;
    const int fk = (lane >> 4) * 8;

    f32x4 acc[4][4];
    #pragma unroll
    for (int mi = 0; mi < 4; ++mi)
        #pragma unroll
        for (int nj = 0; nj < 4; ++nj)
            acc[mi][nj] = (f32x4){0.f, 0.f, 0.f, 0.f};

    for (int kk = 0; kk < KDIM; kk += 32) {
        const uint4 a0 = *(const uint4*)(gAh + kk);
        const uint4 a1 = *(const uint4*)(gAh + kk + 8);
        const uint4 c0 = *(const uint4*)(gAl + kk);
        const uint4 c1 = *(const uint4*)(gAl + kk + 8);
        const uint4 b0 = *(const uint4*)(gBh + kk);
        const uint4 b1 = *(const uint4*)(gBh + kk + 8);
        const uint4 d0 = *(const uint4*)(gBl + kk);
        const uint4 d1 = *(const uint4*)(gBl + kk + 8);
        __syncthreads();
        *(uint2*)&sAh[lws + 0]  = make_uint2(a0.x, a0.y);
        *(uint2*)&sAh[lws + 4]  = make_uint2(a0.z, a0.w);
        *(uint2*)&sAh[lws + 8]  = make_uint2(a1.x, a1.y);
        *(uint2*)&sAh[lws + 12] = make_uint2(a1.z, a1.w);
        *(uint2*)&sAl[lws + 0]  = make_uint2(c0.x, c0.y);
        *(uint2*)&sAl[lws + 4]  = make_uint2(c0.z, c0.w);
        *(uint2*)&sAl[lws + 8]  = make_uint2(c1.x, c1.y);
        *(uint2*)&sAl[lws + 12] = make_uint2(c1.z, c1.w);
        *(uint2*)&sBh[lws + 0]  = make_uint2(b0.x, b0.y);
        *(uint2*)&sBh[lws + 4]  = make_uint2(b0.z, b0.w);
        *(uint2*)&sBh[lws + 8]  = make_uint2(b1.x, b1.y);
        *(uint2*)&sBh[lws + 12] = make_uint2(b1.z, b1.w);
        *(uint2*)&sBl[lws + 0]  = make_uint2(d0.x, d0.y);
        *(uint2*)&sBl[lws + 4]  = make_uint2(d0.z, d0.w);
        *(uint2*)&sBl[lws + 8]  = make_uint2(d1.x, d1.y);
        *(uint2*)&sBl[lws + 12] = make_uint2(d1.z, d1.w);
        __syncthreads();

        bf16x8 fah[4], fal[4], fbh[4], fbl[4];
        #pragma unroll
        for (int i = 0; i < 4; ++i) {
            const int ao = (wr * 64 + i * 16 + frow) * PAD + fk;
            fah[i] = ldsfrag(sAh + ao);
            fal[i] = ldsfrag(sAl + ao);
            const int bo = (wc * 64 + i * 16 + frow) * PAD + fk;
            fbh[i] = ldsfrag(sBh + bo);
            fbl[i] = ldsfrag(sBl + bo);
        }
        #pragma unroll
        for (int mi = 0; mi < 4; ++mi)
            #pragma unroll
            for (int nj = 0; nj < 4; ++nj) {
                acc[mi][nj] = __builtin_amdgcn_mfma_f32_16x16x32_bf16(
                    fah[mi], fbh[nj], acc[mi][nj], 0, 0, 0);
                acc[mi][nj] = __builtin_amdgcn_mfma_f32_16x16x32_bf16(
                    fah[mi], fbl[nj], acc[mi][nj], 0, 0, 0);
                acc[mi][nj] = __builtin_amdgcn_mfma_f32_16x16x32_bf16(
                    fal[mi], fbh[nj], acc[mi][nj], 0, 0, 0);
            }
    }

    // epilogue: D frag layout col = lane&15, row = (lane>>4)*4 + j
    const bool act = (j0 < act_cols);       // block-uniform (2048 % 128 == 0)
    const int rbase = m0 + wr * 64 + (lane >> 4) * 4;
    const int cbase = j0 + wc * 64 + frow;
    #pragma unroll
    for (int mi = 0; mi < 4; ++mi) {
        #pragma unroll
        for (int j = 0; j < 4; ++j) {
            const int row = rbase + mi * 16 + j;
            #pragma unroll
            for (int nj = 0; nj < 4; ++nj) {
                const int col = cbase + nj * 16;
                float v = acc[mi][nj][j];
                if (bias) v += bias[col];
                if (act) v = elu1(v);
                dst[(size_t)row * ldd + col] = v;
            }
        }
    }
}

// ---------------------------------------------------------------------------
// Partial KV = K_feat^T V and ksum, per (b,h), 16-way N split.
// QKV [4096,3072]: cols [0,1024)=Q, [1024,2048)=K, [2048,3072)=V.
// KVp layout: [split s][bh][4160] (4096 KV + 64 ksum)
// ---------------------------------------------------------------------------
__global__ __launch_bounds__(256)
void kv_partial_kernel(const float* __restrict__ QKV, float* __restrict__ KVp)
{
    const int bh = blockIdx.x;
    const int s  = blockIdx.y;
    const int b  = bh >> 4;
    const int h  = bh & 15;
    const int t  = threadIdx.x;

    __shared__ float ks[4][68];
    __shared__ float vs[4][68];

    const int d0 = (t >> 4) * 4;
    const int e0 = (t & 15) * 4;

    float acc[4][4];
    #pragma unroll
    for (int i = 0; i < 4; ++i)
        #pragma unroll
        for (int j = 0; j < 4; ++j) acc[i][j] = 0.f;
    float acc_ks[4] = {0.f, 0.f, 0.f, 0.f};

    const int lrow = t >> 6;
    const int lcol = t & 63;
    const size_t kbase = (size_t)b * N_SEQ * 3072 + 1024 + h * 64 + lcol;
    const size_t vbase = (size_t)b * N_SEQ * 3072 + 2048 + h * 64 + lcol;

    for (int it = 0; it < 32; ++it) {
        const int n0 = s * 128 + it * 4;
        const float kval = QKV[kbase + (size_t)(n0 + lrow) * 3072];
        const float vval = QKV[vbase + (size_t)(n0 + lrow) * 3072];
        __syncthreads();
        ks[lrow][lcol] = kval;
        vs[lrow][lcol] = vval;
        __syncthreads();
        #pragma unroll
        for (int r = 0; r < 4; ++r) {
            const float4 k4 = *(const float4*)&ks[r][d0];
            const float4 v4 = *(const float4*)&vs[r][e0];
            const float ka[4] = {k4.x, k4.y, k4.z, k4.w};
            const float va[4] = {v4.x, v4.y, v4.z, v4.w};
            #pragma unroll
            for (int i = 0; i < 4; ++i)
                #pragma unroll
                for (int j = 0; j < 4; ++j)
                    acc[i][j] += ka[i] * va[j];
            if (e0 == 0) {
                #pragma unroll
                for (int i = 0; i < 4; ++i) acc_ks[i] += ka[i];
            }
        }
    }

    float* outp = KVp + ((size_t)s * 32 + bh) * 4160;
    #pragma unroll
    for (int i = 0; i < 4; ++i) {
        float4 o; o.x = acc[i][0]; o.y = acc[i][1]; o.z = acc[i][2]; o.w = acc[i][3];
        *(float4*)(outp + (d0 + i) * 64 + e0) = o;
    }
    if (e0 == 0) {
        #pragma unroll
        for (int i = 0; i < 4; ++i) outp[4096 + d0 + i] = acc_ks[i];
    }
}

__global__ __launch_bounds__(256)
void kv_reduce_kernel(const float* __restrict__ KVp, float* __restrict__ KVf)
{
    const int idx = blockIdx.x * 256 + threadIdx.x;
    if (idx < 32 * 4160) {
        float s = 0.f;
        #pragma unroll
        for (int i = 0; i < 16; ++i) s += KVp[(size_t)i * (32 * 4160) + idx];
        KVf[idx] = s;
    }
}

// ---------------------------------------------------------------------------
// O1[n, h*64+e] = Z * sum_d q[n,d]*KV[d,e], Z = 1/(q.ksum + 1e-6)
// Output written as bf16 hi/lo pair (feeds final MFMA GEMM).
// ---------------------------------------------------------------------------
__global__ __launch_bounds__(256)
void attn_apply_kernel(const float* __restrict__ QKV, const float* __restrict__ KVf,
                       ushort* __restrict__ O1hi, ushort* __restrict__ O1lo)
{
    const int bh = blockIdx.x;
    const int b = bh >> 4, h = bh & 15;
    const int n0 = blockIdx.y * 16;
    const int t = threadIdx.x;
    const int r  = t >> 4;
    const int e0 = (t & 15) * 4;

    __shared__ float kvs[64][68];
    __shared__ float qs[16][68];
    __shared__ float ksums[64];

    const float* kvb = KVf + (size_t)bh * 4160;
    for (int i = t; i < 4096; i += 256)
        kvs[i >> 6][i & 63] = kvb[i];
    if (t < 64) ksums[t] = kvb[4096 + t];
    {
        const int rr = t >> 4, cc = (t & 15) * 4;
        *(float4*)&qs[rr][cc] =
            *(const float4*)&QKV[(size_t)(b * N_SEQ + n0 + rr) * 3072 + h * 64 + cc];
    }
    __syncthreads();

    float4 acc = {0.f, 0.f, 0.f, 0.f};
    float accz = 0.f;
    #pragma unroll
    for (int d = 0; d < 64; ++d) {
        const float qv = qs[r][d];
        const float4 kvv = *(const float4*)&kvs[d][e0];
        acc.x += qv * kvv.x; acc.y += qv * kvv.y;
        acc.z += qv * kvv.z; acc.w += qv * kvv.w;
        accz += qv * ksums[d];
    }
    const float Z = 1.f / (accz + 1e-6f);
    const float vv[4] = {acc.x * Z, acc.y * Z, acc.z * Z, acc.w * Z};
    ushort hv[4], lv[4];
    #pragma unroll
    for (int j = 0; j < 4; ++j) {
        hv[j] = f2bf(vv[j]);
        lv[j] = f2bf(vv[j] - bf2f(hv[j]));
    }
    const size_t off = (size_t)(b * N_SEQ + n0 + r) * C_DIM + h * 64 + e0;
    short4v H = {(short)hv[0], (short)hv[1], (short)hv[2], (short)hv[3]};
    short4v L = {(short)lv[0], (short)lv[1], (short)lv[2], (short)lv[3]};
    *(short4v*)&O1hi[off] = H;
    *(short4v*)&O1lo[off] = L;
}

extern "C" void kernel_launch(void* const* d_in, const int* in_sizes, int n_in,
                              void* d_out, int out_size, void* d_ws, size_t ws_size,
                              hipStream_t stream)
{
    const float* x   = (const float*)d_in[0];
    const float* Wq  = (const float*)d_in[1];
    const float* Wkv = (const float*)d_in[2];
    const float* Wo  = (const float*)d_in[3];
    const float* bo  = (const float*)d_in[4];
    float* out = (float*)d_out;

    float* ws   = (float*)d_ws;
    float* QKV  = ws;                                  // 4096*3072 f32
    float* KVp  = QKV + (size_t)M_ROWS * 3072;         // 16*32*4160
    float* KVf  = KVp + (size_t)16 * 32 * 4160;        // 32*4160
    ushort* xhi = (ushort*)(KVf + 32 * 4160);          // 4096*1024 bf16 each
    ushort* xlo = xhi + (size_t)M_ROWS * 1024;
    ushort* Whi = xlo + (size_t)M_ROWS * 1024;         // 3072*1024 (Wq;Wkv)
    ushort* Wlo = Whi + (size_t)3072 * 1024;
    ushort* Wohi = Wlo + (size_t)3072 * 1024;          // 1024*1024
    ushort* Wolo = Wohi + (size_t)1024 * 1024;
    ushort* O1hi = xhi;                                // alias: x dead after GEMM1
    ushort* O1lo = xlo;

    // 0. split fp32 -> bf16 hi/lo
    split_hilo_kernel<<<dim3(M_ROWS * 1024 / 8 / 256), 256, 0, stream>>>(x, xhi, xlo, M_ROWS * 1024 / 8);
    split_hilo_kernel<<<dim3(1024 * 1024 / 8 / 256), 256, 0, stream>>>(Wq, Whi, Wlo, 1024 * 1024 / 8);
    split_hilo_kernel<<<dim3(2048 * 1024 / 8 / 256), 256, 0, stream>>>(
        Wkv, Whi + (size_t)1024 * 1024, Wlo + (size_t)1024 * 1024, 2048 * 1024 / 8);
    split_hilo_kernel<<<dim3(1024 * 1024 / 8 / 256), 256, 0, stream>>>(Wo, Wohi, Wolo, 1024 * 1024 / 8);

    // 1. fused q/k/v projections + elu+1 on q,k  (N = 3072)
    gemm_mfma_kernel<<<dim3(M_ROWS / 128, 3072 / 128), 256, 0, stream>>>(
        xhi, xlo, Whi, Wlo, nullptr, QKV, 3072, 2048);

    // 2-3. KV = K^T V + ksum (split + deterministic reduce)
    kv_partial_kernel<<<dim3(32, 16), 256, 0, stream>>>(QKV, KVp);
    kv_reduce_kernel<<<dim3((32 * 4160 + 255) / 256), 256, 0, stream>>>(KVp, KVf);

    // 4. O1 = Z * (q @ KV), bf16 hi/lo out
    attn_apply_kernel<<<dim3(32, 128), 256, 0, stream>>>(QKV, KVf, O1hi, O1lo);

    // 5. final projection + bias
    gemm_mfma_kernel<<<dim3(M_ROWS / 128, 1024 / 128), 256, 0, stream>>>(
        O1hi, O1lo, Wohi, Wolo, bo, out, 1024, 0);
}

// Round 3
// 193.037 us; speedup vs baseline: 2.4675x; 1.1410x over previous
//
#include <hip/hip_runtime.h>
#include <math.h>

#define C_DIM 1024
#define B_SZ 2
#define N_SEQ 2048
#define M_ROWS (B_SZ * N_SEQ)   // 4096
#define KDIM 1024
#define PAD 36                  // old 128^2 kernel LDS pad
#define SLOT_EL 16384           // ushort elements per 32KB pipeline slot

typedef float  f32x4   __attribute__((ext_vector_type(4)));
typedef short  bf16x8  __attribute__((ext_vector_type(8)));
typedef short  short4v __attribute__((ext_vector_type(4)));
typedef short  short8v __attribute__((ext_vector_type(8)));

__device__ __forceinline__ float elu1(float v) {
    return v > 0.f ? v + 1.f : expf(v);
}

__device__ __forceinline__ ushort f2bf(float f) {
    union { float f; unsigned u; } x; x.f = f;
    unsigned r = (x.u + 0x7fffu + ((x.u >> 16) & 1u)) >> 16;  // RNE
    return (ushort)r;
}
__device__ __forceinline__ float bf2f(ushort b) {
    union { unsigned u; float f; } x; x.u = ((unsigned)b) << 16;
    return x.f;
}

__device__ __forceinline__ bf16x8 ldsfrag(const ushort* p) {
    short4v a = *(const short4v*)p;
    short4v b = *(const short4v*)(p + 4);
    return __builtin_shufflevector(a, b, 0, 1, 2, 3, 4, 5, 6, 7);
}

#define VMCNT(n) asm volatile("s_waitcnt vmcnt(" #n ")" ::: "memory")

__device__ __forceinline__ void gl16(const ushort* g, ushort* l) {
    __builtin_amdgcn_global_load_lds(
        (const __attribute__((address_space(1))) unsigned int*)g,
        (__attribute__((address_space(3))) unsigned int*)l,
        16, 0, 0);
}

// ---------------------------------------------------------------------------
// fp32 -> bf16 hi/lo split, 8 elems/thread
// ---------------------------------------------------------------------------
__global__ __launch_bounds__(256)
void split_hilo_kernel(const float* __restrict__ in, ushort* __restrict__ hi,
                       ushort* __restrict__ lo, int n8)
{
    const int i = blockIdx.x * 256 + threadIdx.x;
    if (i >= n8) return;
    const float4 a = ((const float4*)in)[i * 2];
    const float4 b = ((const float4*)in)[i * 2 + 1];
    const float v[8] = {a.x, a.y, a.z, a.w, b.x, b.y, b.z, b.w};
    ushort hv[8], lv[8];
    #pragma unroll
    for (int j = 0; j < 8; ++j) {
        hv[j] = f2bf(v[j]);
        lv[j] = f2bf(v[j] - bf2f(hv[j]));
    }
    short8v H = {(short)hv[0],(short)hv[1],(short)hv[2],(short)hv[3],
                 (short)hv[4],(short)hv[5],(short)hv[6],(short)hv[7]};
    short8v L = {(short)lv[0],(short)lv[1],(short)lv[2],(short)lv[3],
                 (short)lv[4],(short)lv[5],(short)lv[6],(short)lv[7]};
    *(short8v*)&hi[(size_t)i * 8] = H;
    *(short8v*)&lo[(size_t)i * 8] = L;
}

// ---------------------------------------------------------------------------
// GEMM1: QKV = [x][Wq;Wkv]^T, 3-term split-bf16, 256x256 tile, BK=32.
// 8 waves (2M x 4N), wave tile 128x64, mfma_f32_16x16x32_bf16.
// 4-slot LDS unit pipeline (unit = Ah+Bh or Al+Bl, 32KB), counted vmcnt(4),
// raw barriers, XOR-swizzled LDS via pre-swizzled global_load_lds source.
// Grid fixed: 192 blocks = 16m x 12n, XCD-chunk swizzled. act on col<2048.
// ---------------------------------------------------------------------------
__global__ __launch_bounds__(512, 2)
void gemm1_mfma256_kernel(const ushort* __restrict__ Ahi, const ushort* __restrict__ Alo,
                          const ushort* __restrict__ Bhi, const ushort* __restrict__ Blo,
                          float* __restrict__ dst)
{
    extern __shared__ ushort smem[];   // 4 slots x 16384 ushorts (128 KB)

    // bijective XCD-chunk swizzle: 192 = 8 xcd x 24
    const int bid = blockIdx.x;
    const int wg  = (bid & 7) * 24 + (bid >> 3);
    const int m0  = (wg / 12) * 256;
    const int n0  = (wg % 12) * 256;

    const int t    = threadIdx.x;
    const int lane = t & 63;
    const int w    = t >> 6;       // wave 0..7
    const int wr   = w >> 2;       // 0..1  (M half)
    const int wc   = w & 3;        // 0..3  (N quarter)

    // --- staging constants (thread t covers LDS elements t*8..t*8+7 of an issue)
    // linear LDS chunk c = t&3 holds global k-chunk g = c ^ ((row>>1)&3)
    const int gch     = (t & 3) ^ ((t >> 3) & 3);
    const size_t rowA = (size_t)(m0 + (t >> 2)) * KDIM + gch * 8;
    const size_t rowB = (size_t)(n0 + (t >> 2)) * KDIM + gch * 8;
    const int wl      = w * 512;   // per-wave uniform LDS offset within an issue

    // --- fragment constants: lane reads k-chunk (lane>>4) of its row
    const int frow = lane & 15;
    const int cc   = (lane >> 4) ^ ((lane >> 1) & 3);  // swizzled 16B slot
    const int aoff = (wr * 128 + frow) * 32 + cc * 8;
    const int boff = 8192 + (wc * 64 + frow) * 32 + cc * 8;

    f32x4 acc[8][4];
    #pragma unroll
    for (int mi = 0; mi < 8; ++mi)
        #pragma unroll
        for (int nj = 0; nj < 4; ++nj)
            acc[mi][nj] = (f32x4){0.f, 0.f, 0.f, 0.f};

    // stage one unit (A-tile + B-tile for one precision, one K-tile) = 4 issues
    #define STAGE(srcA, srcB, slotp, koff)                                   \
        do {                                                                 \
            ushort* sl_ = (slotp);                                           \
            gl16((srcA) + rowA + (koff),          sl_ + wl);                 \
            gl16((srcA) + rowA + 131072 + (koff), sl_ + 4096 + wl);          \
            gl16((srcB) + rowB + (koff),          sl_ + 8192 + wl);          \
            gl16((srcB) + rowB + 131072 + (koff), sl_ + 12288 + wl);         \
        } while (0)

    // prologue: units 0 (hi, kt0 -> slot0) and 1 (lo, kt0 -> slot1)
    STAGE(Ahi, Bhi, smem, 0);
    STAGE(Alo, Blo, smem + SLOT_EL, 0);

    bf16x8 ah[8];

    #pragma unroll 1
    for (int kt = 0; kt < 32; ++kt) {
        ushort* sh_base = smem + ((kt & 1) << 1) * SLOT_EL;  // hi slot
        ushort* sl_base = sh_base + SLOT_EL;                 // lo slot
        const int koff_next = (kt + 1) * 32;

        // ---------------- hi unit (u = 2kt): acc += Ah*Bh ----------------
        VMCNT(4);
        __builtin_amdgcn_s_barrier();
        if (kt < 31)
            STAGE(Ahi, Bhi, smem + ((2 * kt + 2) & 3) * SLOT_EL, koff_next);
        {
            #pragma unroll
            for (int mi = 0; mi < 8; ++mi)
                ah[mi] = *(const bf16x8*)(sh_base + aoff + mi * 512);
            bf16x8 bh[4];
            #pragma unroll
            for (int nj = 0; nj < 4; ++nj)
                bh[nj] = *(const bf16x8*)(sh_base + boff + nj * 512);
            __builtin_amdgcn_s_setprio(1);
            #pragma unroll
            for (int mi = 0; mi < 8; ++mi)
                #pragma unroll
                for (int nj = 0; nj < 4; ++nj)
                    acc[mi][nj] = __builtin_amdgcn_mfma_f32_16x16x32_bf16(
                        ah[mi], bh[nj], acc[mi][nj], 0, 0, 0);
            __builtin_amdgcn_s_setprio(0);
        }

        // ------------- lo unit (u = 2kt+1): acc += Ah*Bl + Al*Bh -------------
        if (kt < 31) { VMCNT(4); } else { VMCNT(0); }
        __builtin_amdgcn_s_barrier();
        if (kt < 31)
            STAGE(Alo, Blo, smem + ((2 * kt + 3) & 3) * SLOT_EL, koff_next);
        {
            bf16x8 bl[4], bh2[4];
            #pragma unroll
            for (int nj = 0; nj < 4; ++nj) {
                bl[nj]  = *(const bf16x8*)(sl_base + boff + nj * 512);
                bh2[nj] = *(const bf16x8*)(sh_base + boff + nj * 512);
            }
            __builtin_amdgcn_s_setprio(1);
            #pragma unroll
            for (int mi = 0; mi < 8; ++mi)
                #pragma unroll
                for (int nj = 0; nj < 4; ++nj)
                    acc[mi][nj] = __builtin_amdgcn_mfma_f32_16x16x32_bf16(
                        ah[mi], bl[nj], acc[mi][nj], 0, 0, 0);
            __builtin_amdgcn_s_setprio(0);
            bf16x8 al[8];
            #pragma unroll
            for (int mi = 0; mi < 8; ++mi)
                al[mi] = *(const bf16x8*)(sl_base + aoff + mi * 512);
            __builtin_amdgcn_s_setprio(1);
            #pragma unroll
            for (int mi = 0; mi < 8; ++mi)
                #pragma unroll
                for (int nj = 0; nj < 4; ++nj)
                    acc[mi][nj] = __builtin_amdgcn_mfma_f32_16x16x32_bf16(
                        al[mi], bh2[nj], acc[mi][nj], 0, 0, 0);
            __builtin_amdgcn_s_setprio(0);
        }
    }
    #undef STAGE

    // epilogue: D frag col = lane&15, row = (lane>>4)*4 + j
    const int erow  = m0 + wr * 128 + (lane >> 4) * 4;
    const int ecol0 = n0 + wc * 64 + (lane & 15);
    #pragma unroll
    for (int mi = 0; mi < 8; ++mi) {
        #pragma unroll
        for (int nj = 0; nj < 4; ++nj) {
            const int col = ecol0 + nj * 16;
            const bool act = col < 2048;
            #pragma unroll
            for (int j = 0; j < 4; ++j) {
                float v = acc[mi][nj][j];
                if (act) v = elu1(v);
                dst[(size_t)(erow + mi * 16 + j) * 3072 + col] = v;
            }
        }
    }
}

// ---------------------------------------------------------------------------
// 128x128 split-bf16 MFMA GEMM (kept for the final projection; full CU fill)
// ---------------------------------------------------------------------------
__global__ __launch_bounds__(256)
void gemm_mfma_kernel(const ushort* __restrict__ Ahi, const ushort* __restrict__ Alo,
                      const ushort* __restrict__ Bhi, const ushort* __restrict__ Blo,
                      const float* __restrict__ bias, float* __restrict__ dst,
                      int ldd, int act_cols)
{
    __shared__ ushort sAh[128 * PAD];
    __shared__ ushort sAl[128 * PAD];
    __shared__ ushort sBh[128 * PAD];
    __shared__ ushort sBl[128 * PAD];

    const int m0 = blockIdx.x * 128;
    const int j0 = blockIdx.y * 128;
    const int t = threadIdx.x;
    const int lane = t & 63;
    const int w = t >> 6;
    const int wr = w >> 1, wc = w & 1;

    const int lr = t >> 1;
    const int half = t & 1;
    const ushort* gAh = Ahi + (size_t)(m0 + lr) * KDIM + half * 16;
    const ushort* gAl = Alo + (size_t)(m0 + lr) * KDIM + half * 16;
    const ushort* gBh = Bhi + (size_t)(j0 + lr) * KDIM + half * 16;
    const ushort* gBl = Blo + (size_t)(j0 + lr) * KDIM + half * 16;
    const int lws = lr * PAD + half * 16;

    const int frow = lane & 15;
    const int fk = (lane >> 4) * 8;

    f32x4 acc[4][4];
    #pragma unroll
    for (int mi = 0; mi < 4; ++mi)
        #pragma unroll
        for (int nj = 0; nj < 4; ++nj)
            acc[mi][nj] = (f32x4){0.f, 0.f, 0.f, 0.f};

    for (int kk = 0; kk < KDIM; kk += 32) {
        const uint4 a0 = *(const uint4*)(gAh + kk);
        const uint4 a1 = *(const uint4*)(gAh + kk + 8);
        const uint4 c0 = *(const uint4*)(gAl + kk);
        const uint4 c1 = *(const uint4*)(gAl + kk + 8);
        const uint4 b0 = *(const uint4*)(gBh + kk);
        const uint4 b1 = *(const uint4*)(gBh + kk + 8);
        const uint4 d0 = *(const uint4*)(gBl + kk);
        const uint4 d1 = *(const uint4*)(gBl + kk + 8);
        __syncthreads();
        *(uint2*)&sAh[lws + 0]  = make_uint2(a0.x, a0.y);
        *(uint2*)&sAh[lws + 4]  = make_uint2(a0.z, a0.w);
        *(uint2*)&sAh[lws + 8]  = make_uint2(a1.x, a1.y);
        *(uint2*)&sAh[lws + 12] = make_uint2(a1.z, a1.w);
        *(uint2*)&sAl[lws + 0]  = make_uint2(c0.x, c0.y);
        *(uint2*)&sAl[lws + 4]  = make_uint2(c0.z, c0.w);
        *(uint2*)&sAl[lws + 8]  = make_uint2(c1.x, c1.y);
        *(uint2*)&sAl[lws + 12] = make_uint2(c1.z, c1.w);
        *(uint2*)&sBh[lws + 0]  = make_uint2(b0.x, b0.y);
        *(uint2*)&sBh[lws + 4]  = make_uint2(b0.z, b0.w);
        *(uint2*)&sBh[lws + 8]  = make_uint2(b1.x, b1.y);
        *(uint2*)&sBh[lws + 12] = make_uint2(b1.z, b1.w);
        *(uint2*)&sBl[lws + 0]  = make_uint2(d0.x, d0.y);
        *(uint2*)&sBl[lws + 4]  = make_uint2(d0.z, d0.w);
        *(uint2*)&sBl[lws + 8]  = make_uint2(d1.x, d1.y);
        *(uint2*)&sBl[lws + 12] = make_uint2(d1.z, d1.w);
        __syncthreads();

        bf16x8 fah[4], fal[4], fbh[4], fbl[4];
        #pragma unroll
        for (int i = 0; i < 4; ++i) {
            const int ao = (wr * 64 + i * 16 + frow) * PAD + fk;
            fah[i] = ldsfrag(sAh + ao);
            fal[i] = ldsfrag(sAl + ao);
            const int bo = (wc * 64 + i * 16 + frow) * PAD + fk;
            fbh[i] = ldsfrag(sBh + bo);
            fbl[i] = ldsfrag(sBl + bo);
        }
        #pragma unroll
        for (int mi = 0; mi < 4; ++mi)
            #pragma unroll
            for (int nj = 0; nj < 4; ++nj) {
                acc[mi][nj] = __builtin_amdgcn_mfma_f32_16x16x32_bf16(
                    fah[mi], fbh[nj], acc[mi][nj], 0, 0, 0);
                acc[mi][nj] = __builtin_amdgcn_mfma_f32_16x16x32_bf16(
                    fah[mi], fbl[nj], acc[mi][nj], 0, 0, 0);
                acc[mi][nj] = __builtin_amdgcn_mfma_f32_16x16x32_bf16(
                    fal[mi], fbh[nj], acc[mi][nj], 0, 0, 0);
            }
    }

    const bool act = (j0 < act_cols);
    const int rbase = m0 + wr * 64 + (lane >> 4) * 4;
    const int cbase = j0 + wc * 64 + frow;
    #pragma unroll
    for (int mi = 0; mi < 4; ++mi) {
        #pragma unroll
        for (int j = 0; j < 4; ++j) {
            const int row = rbase + mi * 16 + j;
            #pragma unroll
            for (int nj = 0; nj < 4; ++nj) {
                const int col = cbase + nj * 16;
                float v = acc[mi][nj][j];
                if (bias) v += bias[col];
                if (act) v = elu1(v);
                dst[(size_t)row * ldd + col] = v;
            }
        }
    }
}

// ---------------------------------------------------------------------------
// Partial KV = K_feat^T V and ksum, per (b,h), 16-way N split.
// ---------------------------------------------------------------------------
__global__ __launch_bounds__(256)
void kv_partial_kernel(const float* __restrict__ QKV, float* __restrict__ KVp)
{
    const int bh = blockIdx.x;
    const int s  = blockIdx.y;
    const int b  = bh >> 4;
    const int h  = bh & 15;
    const int t  = threadIdx.x;

    __shared__ float ks[4][68];
    __shared__ float vs[4][68];

    const int d0 = (t >> 4) * 4;
    const int e0 = (t & 15) * 4;

    float acc[4][4];
    #pragma unroll
    for (int i = 0; i < 4; ++i)
        #pragma unroll
        for (int j = 0; j < 4; ++j) acc[i][j] = 0.f;
    float acc_ks[4] = {0.f, 0.f, 0.f, 0.f};

    const int lrow = t >> 6;
    const int lcol = t & 63;
    const size_t kbase = (size_t)b * N_SEQ * 3072 + 1024 + h * 64 + lcol;
    const size_t vbase = (size_t)b * N_SEQ * 3072 + 2048 + h * 64 + lcol;

    for (int it = 0; it < 32; ++it) {
        const int n0 = s * 128 + it * 4;
        const float kval = QKV[kbase + (size_t)(n0 + lrow) * 3072];
        const float vval = QKV[vbase + (size_t)(n0 + lrow) * 3072];
        __syncthreads();
        ks[lrow][lcol] = kval;
        vs[lrow][lcol] = vval;
        __syncthreads();
        #pragma unroll
        for (int r = 0; r < 4; ++r) {
            const float4 k4 = *(const float4*)&ks[r][d0];
            const float4 v4 = *(const float4*)&vs[r][e0];
            const float ka[4] = {k4.x, k4.y, k4.z, k4.w};
            const float va[4] = {v4.x, v4.y, v4.z, v4.w};
            #pragma unroll
            for (int i = 0; i < 4; ++i)
                #pragma unroll
                for (int j = 0; j < 4; ++j)
                    acc[i][j] += ka[i] * va[j];
            if (e0 == 0) {
                #pragma unroll
                for (int i = 0; i < 4; ++i) acc_ks[i] += ka[i];
            }
        }
    }

    float* outp = KVp + ((size_t)s * 32 + bh) * 4160;
    #pragma unroll
    for (int i = 0; i < 4; ++i) {
        float4 o; o.x = acc[i][0]; o.y = acc[i][1]; o.z = acc[i][2]; o.w = acc[i][3];
        *(float4*)(outp + (d0 + i) * 64 + e0) = o;
    }
    if (e0 == 0) {
        #pragma unroll
        for (int i = 0; i < 4; ++i) outp[4096 + d0 + i] = acc_ks[i];
    }
}

__global__ __launch_bounds__(256)
void kv_reduce_kernel(const float* __restrict__ KVp, float* __restrict__ KVf)
{
    const int idx = blockIdx.x * 256 + threadIdx.x;
    if (idx < 32 * 4160) {
        float s = 0.f;
        #pragma unroll
        for (int i = 0; i < 16; ++i) s += KVp[(size_t)i * (32 * 4160) + idx];
        KVf[idx] = s;
    }
}

// ---------------------------------------------------------------------------
// O1[n, h*64+e] = Z * sum_d q[n,d]*KV[d,e], Z = 1/(q.ksum + 1e-6); bf16 hi/lo out
// ---------------------------------------------------------------------------
__global__ __launch_bounds__(256)
void attn_apply_kernel(const float* __restrict__ QKV, const float* __restrict__ KVf,
                       ushort* __restrict__ O1hi, ushort* __restrict__ O1lo)
{
    const int bh = blockIdx.x;
    const int b = bh >> 4, h = bh & 15;
    const int n0 = blockIdx.y * 16;
    const int t = threadIdx.x;
    const int r  = t >> 4;
    const int e0 = (t & 15) * 4;

    __shared__ float kvs[64][68];
    __shared__ float qs[16][68];
    __shared__ float ksums[64];

    const float* kvb = KVf + (size_t)bh * 4160;
    for (int i = t; i < 4096; i += 256)
        kvs[i >> 6][i & 63] = kvb[i];
    if (t < 64) ksums[t] = kvb[4096 + t];
    {
        const int rr = t >> 4, cc2 = (t & 15) * 4;
        *(float4*)&qs[rr][cc2] =
            *(const float4*)&QKV[(size_t)(b * N_SEQ + n0 + rr) * 3072 + h * 64 + cc2];
    }
    __syncthreads();

    float4 acc = {0.f, 0.f, 0.f, 0.f};
    float accz = 0.f;
    #pragma unroll
    for (int d = 0; d < 64; ++d) {
        const float qv = qs[r][d];
        const float4 kvv = *(const float4*)&kvs[d][e0];
        acc.x += qv * kvv.x; acc.y += qv * kvv.y;
        acc.z += qv * kvv.z; acc.w += qv * kvv.w;
        accz += qv * ksums[d];
    }
    const float Z = 1.f / (accz + 1e-6f);
    const float vv[4] = {acc.x * Z, acc.y * Z, acc.z * Z, acc.w * Z};
    ushort hv[4], lv[4];
    #pragma unroll
    for (int j = 0; j < 4; ++j) {
        hv[j] = f2bf(vv[j]);
        lv[j] = f2bf(vv[j] - bf2f(hv[j]));
    }
    const size_t off = (size_t)(b * N_SEQ + n0 + r) * C_DIM + h * 64 + e0;
    short4v H = {(short)hv[0], (short)hv[1], (short)hv[2], (short)hv[3]};
    short4v L = {(short)lv[0], (short)lv[1], (short)lv[2], (short)lv[3]};
    *(short4v*)&O1hi[off] = H;
    *(short4v*)&O1lo[off] = L;
}

extern "C" void kernel_launch(void* const* d_in, const int* in_sizes, int n_in,
                              void* d_out, int out_size, void* d_ws, size_t ws_size,
                              hipStream_t stream)
{
    const float* x   = (const float*)d_in[0];
    const float* Wq  = (const float*)d_in[1];
    const float* Wkv = (const float*)d_in[2];
    const float* Wo  = (const float*)d_in[3];
    const float* bo  = (const float*)d_in[4];
    float* out = (float*)d_out;

    float* ws   = (float*)d_ws;
    float* QKV  = ws;                                  // 4096*3072 f32
    float* KVp  = QKV + (size_t)M_ROWS * 3072;         // 16*32*4160
    float* KVf  = KVp + (size_t)16 * 32 * 4160;        // 32*4160
    ushort* xhi = (ushort*)(KVf + 32 * 4160);          // 4096*1024 bf16 each
    ushort* xlo = xhi + (size_t)M_ROWS * 1024;
    ushort* Whi = xlo + (size_t)M_ROWS * 1024;         // 3072*1024 (Wq;Wkv)
    ushort* Wlo = Whi + (size_t)3072 * 1024;
    ushort* Wohi = Wlo + (size_t)3072 * 1024;          // 1024*1024
    ushort* Wolo = Wohi + (size_t)1024 * 1024;
    ushort* O1hi = xhi;                                // alias: x dead after GEMM1
    ushort* O1lo = xlo;

    hipFuncSetAttribute((const void*)gemm1_mfma256_kernel,
                        hipFuncAttributeMaxDynamicSharedMemorySize, 131072);

    // 0. split fp32 -> bf16 hi/lo
    split_hilo_kernel<<<dim3(M_ROWS * 1024 / 8 / 256), 256, 0, stream>>>(x, xhi, xlo, M_ROWS * 1024 / 8);
    split_hilo_kernel<<<dim3(1024 * 1024 / 8 / 256), 256, 0, stream>>>(Wq, Whi, Wlo, 1024 * 1024 / 8);
    split_hilo_kernel<<<dim3(2048 * 1024 / 8 / 256), 256, 0, stream>>>(
        Wkv, Whi + (size_t)1024 * 1024, Wlo + (size_t)1024 * 1024, 2048 * 1024 / 8);
    split_hilo_kernel<<<dim3(1024 * 1024 / 8 / 256), 256, 0, stream>>>(Wo, Wohi, Wolo, 1024 * 1024 / 8);

    // 1. fused q/k/v projections + elu+1 on q,k (pipelined 256^2 kernel)
    gemm1_mfma256_kernel<<<dim3(192), 512, 131072, stream>>>(xhi, xlo, Whi, Wlo, QKV);

    // 2-3. KV = K^T V + ksum (split + deterministic reduce)
    kv_partial_kernel<<<dim3(32, 16), 256, 0, stream>>>(QKV, KVp);
    kv_reduce_kernel<<<dim3((32 * 4160 + 255) / 256), 256, 0, stream>>>(KVp, KVf);

    // 4. O1 = Z * (q @ KV), bf16 hi/lo out
    attn_apply_kernel<<<dim3(32, 128), 256, 0, stream>>>(QKV, KVf, O1hi, O1lo);

    // 5. final projection + bias
    gemm_mfma_kernel<<<dim3(M_ROWS / 128, 1024 / 128), 256, 0, stream>>>(
        O1hi, O1lo, Wohi, Wolo, bo, out, 1024, 0);
}

// Round 4
// 175.200 us; speedup vs baseline: 2.7187x; 1.1018x over previous
//
#include <hip/hip_runtime.h>
#include <math.h>

#define C_DIM 1024
#define B_SZ 2
#define N_SEQ 2048
#define M_ROWS (B_SZ * N_SEQ)   // 4096
#define KDIM 1024
#define SLOT_EL 16384           // ushort elements per 32KB gemm1 slot
#define SLOT2_EL 6144           // ushort elements per 12KB gemm2 slot

typedef float  f32x4   __attribute__((ext_vector_type(4)));
typedef float  f32x16  __attribute__((ext_vector_type(16)));
typedef short  bf16x8  __attribute__((ext_vector_type(8)));
typedef short  short4v __attribute__((ext_vector_type(4)));
typedef short  short8v __attribute__((ext_vector_type(8)));

__device__ __forceinline__ float elu1(float v) {
    return v > 0.f ? v + 1.f : expf(v);
}

__device__ __forceinline__ ushort f2bf(float f) {
    union { float f; unsigned u; } x; x.f = f;
    unsigned r = (x.u + 0x7fffu + ((x.u >> 16) & 1u)) >> 16;  // RNE
    return (ushort)r;
}
__device__ __forceinline__ float bf2f(ushort b) {
    union { unsigned u; float f; } x; x.u = ((unsigned)b) << 16;
    return x.f;
}

#define VMCNT(n) asm volatile("s_waitcnt vmcnt(" #n ")" ::: "memory")

__device__ __forceinline__ void gl16(const ushort* g, ushort* l) {
    __builtin_amdgcn_global_load_lds(
        (const __attribute__((address_space(1))) unsigned int*)g,
        (__attribute__((address_space(3))) unsigned int*)l,
        16, 0, 0);
}

// ---------------------------------------------------------------------------
// fp32 -> bf16 hi/lo split for all 4 inputs in one launch. 8 elems/thread.
// Segments (in 8-elem groups): x 524288 | Wq 131072 | Wkv 262144 | Wo 131072
// ---------------------------------------------------------------------------
__global__ __launch_bounds__(256)
void split_all_kernel(const float* __restrict__ x, const float* __restrict__ Wq,
                      const float* __restrict__ Wkv, const float* __restrict__ Wo,
                      ushort* __restrict__ xhi, ushort* __restrict__ xlo,
                      ushort* __restrict__ Whi, ushort* __restrict__ Wlo,
                      ushort* __restrict__ Wohi, ushort* __restrict__ Wolo)
{
    const int i = blockIdx.x * 256 + threadIdx.x;   // 0..1048575
    const float* src; ushort* dh; ushort* dl; int off;
    if (i < 524288)        { src = x;   dh = xhi;  dl = xlo;  off = i; }
    else if (i < 655360)   { src = Wq;  dh = Whi;  dl = Wlo;  off = i - 524288; }
    else if (i < 917504)   { src = Wkv; dh = Whi + (1u << 20); dl = Wlo + (1u << 20); off = i - 655360; }
    else                   { src = Wo;  dh = Wohi; dl = Wolo; off = i - 917504; }

    const float4 a = ((const float4*)src)[off * 2];
    const float4 b = ((const float4*)src)[off * 2 + 1];
    const float v[8] = {a.x, a.y, a.z, a.w, b.x, b.y, b.z, b.w};
    ushort hv[8], lv[8];
    #pragma unroll
    for (int j = 0; j < 8; ++j) {
        hv[j] = f2bf(v[j]);
        lv[j] = f2bf(v[j] - bf2f(hv[j]));
    }
    short8v H = {(short)hv[0],(short)hv[1],(short)hv[2],(short)hv[3],
                 (short)hv[4],(short)hv[5],(short)hv[6],(short)hv[7]};
    short8v L = {(short)lv[0],(short)lv[1],(short)lv[2],(short)lv[3],
                 (short)lv[4],(short)lv[5],(short)lv[6],(short)lv[7]};
    *(short8v*)&dh[(size_t)off * 8] = H;
    *(short8v*)&dl[(size_t)off * 8] = L;
}

// ---------------------------------------------------------------------------
// GEMM1: QKV = [x][Wq;Wkv]^T, 3-term split-bf16, 256x256 tile, BK=32,
// mfma_f32_32x32x16_bf16 frags. 8 waves (2M x 4N), wave tile 128x64.
// 4-slot LDS hi/lo pipeline, counted vmcnt(4), XOR-swizzled LDS via
// pre-swizzled global_load_lds source. Grid 192 = 16m x 12n, XCD swizzle.
// ---------------------------------------------------------------------------
__global__ __launch_bounds__(512, 2)
void gemm1_mfma256_kernel(const ushort* __restrict__ Ahi, const ushort* __restrict__ Alo,
                          const ushort* __restrict__ Bhi, const ushort* __restrict__ Blo,
                          float* __restrict__ dst)
{
    extern __shared__ ushort smem[];   // 4 slots x 16384 ushorts (128 KB)

    const int bid = blockIdx.x;
    const int wg  = (bid & 7) * 24 + (bid >> 3);    // bijective: 192 = 8*24
    const int m0  = (wg / 12) * 256;
    const int n0  = (wg % 12) * 256;

    const int t    = threadIdx.x;
    const int lane = t & 63;
    const int w    = t >> 6;
    const int wr   = w >> 2;       // 0..1
    const int wc   = w & 3;        // 0..3

    // staging: thread t -> row t>>2, LDS chunk t&3 holds global chunk g
    const int gch     = (t & 3) ^ ((t >> 3) & 3);
    const size_t rowA = (size_t)(m0 + (t >> 2)) * KDIM + gch * 8;
    const size_t rowB = (size_t)(n0 + (t >> 2)) * KDIM + gch * 8;
    const int wl      = w * 512;

    // fragment addressing (32x32x16: row = lane&31, k = (lane>>5)*8 + j)
    const int lane31 = lane & 31;
    const int ksel   = lane >> 5;
    const int swz    = (lane >> 1) & 3;
    const int ck0    = ((0 + ksel) ^ swz) * 8;      // k-chunk 0 (k 0..15)
    const int ck1    = ((2 + ksel) ^ swz) * 8;      // k-chunk 1 (k 16..31)
    const int arow   = (wr * 128 + lane31) * 32;
    const int brow   = 8192 + (wc * 64 + lane31) * 32;

    f32x16 acc[4][2];
    #pragma unroll
    for (int mi = 0; mi < 4; ++mi)
        #pragma unroll
        for (int nj = 0; nj < 2; ++nj)
            #pragma unroll
            for (int e = 0; e < 16; ++e)
                acc[mi][nj][e] = 0.f;

    #define STAGE(srcA, srcB, slotp, koff)                                   \
        do {                                                                 \
            ushort* sl_ = (slotp);                                           \
            gl16((srcA) + rowA + (koff),          sl_ + wl);                 \
            gl16((srcA) + rowA + 131072 + (koff), sl_ + 4096 + wl);          \
            gl16((srcB) + rowB + (koff),          sl_ + 8192 + wl);          \
            gl16((srcB) + rowB + 131072 + (koff), sl_ + 12288 + wl);         \
        } while (0)

    STAGE(Ahi, Bhi, smem, 0);
    STAGE(Alo, Blo, smem + SLOT_EL, 0);

    #pragma unroll 1
    for (int kt = 0; kt < 32; ++kt) {
        ushort* sh_base = smem + ((kt & 1) << 1) * SLOT_EL;
        ushort* sl_base = sh_base + SLOT_EL;
        const int koff_next = (kt + 1) * 32;

        // ---------------- hi unit: acc += Ah*Bh ----------------
        VMCNT(4);
        __builtin_amdgcn_s_barrier();
        if (kt < 31)
            STAGE(Ahi, Bhi, smem + ((2 * kt + 2) & 3) * SLOT_EL, koff_next);

        bf16x8 ah[4][2], bh[2][2];
        #pragma unroll
        for (int mi = 0; mi < 4; ++mi) {
            ah[mi][0] = *(const bf16x8*)(sh_base + arow + mi * 1024 + ck0);
            ah[mi][1] = *(const bf16x8*)(sh_base + arow + mi * 1024 + ck1);
        }
        #pragma unroll
        for (int nj = 0; nj < 2; ++nj) {
            bh[nj][0] = *(const bf16x8*)(sh_base + brow + nj * 1024 + ck0);
            bh[nj][1] = *(const bf16x8*)(sh_base + brow + nj * 1024 + ck1);
        }
        __builtin_amdgcn_s_setprio(1);
        #pragma unroll
        for (int c = 0; c < 2; ++c)
            #pragma unroll
            for (int mi = 0; mi < 4; ++mi)
                #pragma unroll
                for (int nj = 0; nj < 2; ++nj)
                    acc[mi][nj] = __builtin_amdgcn_mfma_f32_32x32x16_bf16(
                        ah[mi][c], bh[nj][c], acc[mi][nj], 0, 0, 0);
        __builtin_amdgcn_s_setprio(0);

        // ------------- lo unit: acc += Ah*Bl + Al*Bh -------------
        if (kt < 31) { VMCNT(4); } else { VMCNT(0); }
        __builtin_amdgcn_s_barrier();
        if (kt < 31)
            STAGE(Alo, Blo, smem + ((2 * kt + 3) & 3) * SLOT_EL, koff_next);

        {
            bf16x8 bl[2][2];
            #pragma unroll
            for (int nj = 0; nj < 2; ++nj) {
                bl[nj][0] = *(const bf16x8*)(sl_base + brow + nj * 1024 + ck0);
                bl[nj][1] = *(const bf16x8*)(sl_base + brow + nj * 1024 + ck1);
            }
            __builtin_amdgcn_s_setprio(1);
            #pragma unroll
            for (int c = 0; c < 2; ++c)
                #pragma unroll
                for (int mi = 0; mi < 4; ++mi)
                    #pragma unroll
                    for (int nj = 0; nj < 2; ++nj)
                        acc[mi][nj] = __builtin_amdgcn_mfma_f32_32x32x16_bf16(
                            ah[mi][c], bl[nj][c], acc[mi][nj], 0, 0, 0);
            __builtin_amdgcn_s_setprio(0);
            bf16x8 al[4][2];
            #pragma unroll
            for (int mi = 0; mi < 4; ++mi) {
                al[mi][0] = *(const bf16x8*)(sl_base + arow + mi * 1024 + ck0);
                al[mi][1] = *(const bf16x8*)(sl_base + arow + mi * 1024 + ck1);
            }
            __builtin_amdgcn_s_setprio(1);
            #pragma unroll
            for (int c = 0; c < 2; ++c)
                #pragma unroll
                for (int mi = 0; mi < 4; ++mi)
                    #pragma unroll
                    for (int nj = 0; nj < 2; ++nj)
                        acc[mi][nj] = __builtin_amdgcn_mfma_f32_32x32x16_bf16(
                            al[mi][c], bh[nj][c], acc[mi][nj], 0, 0, 0);
            __builtin_amdgcn_s_setprio(0);
        }
    }
    #undef STAGE

    // epilogue: 32x32 D layout: col = lane&31, row = (r&3)+8*(r>>2)+4*(lane>>5)
    const int ecol0 = n0 + wc * 64 + lane31;
    const int erow0 = m0 + wr * 128 + ksel * 4;
    #pragma unroll
    for (int mi = 0; mi < 4; ++mi) {
        #pragma unroll
        for (int nj = 0; nj < 2; ++nj) {
            const int col = ecol0 + nj * 32;
            const bool act = col < 2048;
            #pragma unroll
            for (int r = 0; r < 16; ++r) {
                const int row = erow0 + mi * 32 + (r & 3) + 8 * (r >> 2);
                float v = acc[mi][nj][r];
                if (act) v = elu1(v);
                dst[(size_t)row * 3072 + col] = v;
            }
        }
    }
}

// ---------------------------------------------------------------------------
// GEMM2: out = O1 @ Wo^T + bo. 64x128 tile, BK=32, 4 waves (1M x 4N),
// wave tile 64x32, 32x32x16 frags, 4-slot hi/lo pipeline, vmcnt(3).
// Grid 512 = 64m x 8n (2 full CU waves), 48KB LDS -> 3 blocks/CU.
// ---------------------------------------------------------------------------
__global__ __launch_bounds__(256, 3)
void gemm2_mfma_kernel(const ushort* __restrict__ Ahi, const ushort* __restrict__ Alo,
                       const ushort* __restrict__ Bhi, const ushort* __restrict__ Blo,
                       const float* __restrict__ bias, float* __restrict__ dst)
{
    __shared__ ushort smem[4 * SLOT2_EL];   // 48 KB

    const int bid = blockIdx.x;
    const int wg  = (bid & 7) * 64 + (bid >> 3);    // bijective: 512 = 8*64
    const int m0  = (wg >> 3) * 64;
    const int n0  = (wg & 7) * 128;

    const int t    = threadIdx.x;
    const int lane = t & 63;
    const int w    = t >> 6;      // 0..3 (N quarters)

    const int gch     = (t & 3) ^ ((t >> 3) & 3);
    const size_t rowA = (size_t)(m0 + (t >> 2)) * KDIM + gch * 8;
    const size_t rowB = (size_t)(n0 + (t >> 2)) * KDIM + gch * 8;
    const int wl      = w * 512;

    const int lane31 = lane & 31;
    const int ksel   = lane >> 5;
    const int swz    = (lane >> 1) & 3;
    const int ck0    = ((0 + ksel) ^ swz) * 8;
    const int ck1    = ((2 + ksel) ^ swz) * 8;
    const int arow   = lane31 * 32;
    const int brow   = 2048 + (w * 32 + lane31) * 32;

    f32x16 acc[2];
    #pragma unroll
    for (int mi = 0; mi < 2; ++mi)
        #pragma unroll
        for (int e = 0; e < 16; ++e)
            acc[mi][e] = 0.f;

    #define STAGE2(srcA, srcB, slotp, koff)                                  \
        do {                                                                 \
            ushort* sl_ = (slotp);                                           \
            gl16((srcA) + rowA + (koff),         sl_ + wl);                  \
            gl16((srcB) + rowB + (koff),         sl_ + 2048 + wl);           \
            gl16((srcB) + rowB + 65536 + (koff), sl_ + 4096 + wl);           \
        } while (0)

    STAGE2(Ahi, Bhi, smem, 0);
    STAGE2(Alo, Blo, smem + SLOT2_EL, 0);

    #pragma unroll 1
    for (int kt = 0; kt < 32; ++kt) {
        ushort* sh_base = smem + ((kt & 1) << 1) * SLOT2_EL;
        ushort* sl_base = sh_base + SLOT2_EL;
        const int koff_next = (kt + 1) * 32;

        VMCNT(3);
        __builtin_amdgcn_s_barrier();
        if (kt < 31)
            STAGE2(Ahi, Bhi, smem + ((2 * kt + 2) & 3) * SLOT2_EL, koff_next);

        bf16x8 ah[2][2], bh[2];
        #pragma unroll
        for (int mi = 0; mi < 2; ++mi) {
            ah[mi][0] = *(const bf16x8*)(sh_base + arow + mi * 1024 + ck0);
            ah[mi][1] = *(const bf16x8*)(sh_base + arow + mi * 1024 + ck1);
        }
        bh[0] = *(const bf16x8*)(sh_base + brow + ck0);
        bh[1] = *(const bf16x8*)(sh_base + brow + ck1);
        __builtin_amdgcn_s_setprio(1);
        #pragma unroll
        for (int c = 0; c < 2; ++c)
            #pragma unroll
            for (int mi = 0; mi < 2; ++mi)
                acc[mi] = __builtin_amdgcn_mfma_f32_32x32x16_bf16(
                    ah[mi][c], bh[c], acc[mi], 0, 0, 0);
        __builtin_amdgcn_s_setprio(0);

        if (kt < 31) { VMCNT(3); } else { VMCNT(0); }
        __builtin_amdgcn_s_barrier();
        if (kt < 31)
            STAGE2(Alo, Blo, smem + ((2 * kt + 3) & 3) * SLOT2_EL, koff_next);

        {
            bf16x8 bl[2];
            bl[0] = *(const bf16x8*)(sl_base + brow + ck0);
            bl[1] = *(const bf16x8*)(sl_base + brow + ck1);
            __builtin_amdgcn_s_setprio(1);
            #pragma unroll
            for (int c = 0; c < 2; ++c)
                #pragma unroll
                for (int mi = 0; mi < 2; ++mi)
                    acc[mi] = __builtin_amdgcn_mfma_f32_32x32x16_bf16(
                        ah[mi][c], bl[c], acc[mi], 0, 0, 0);
            __builtin_amdgcn_s_setprio(0);
            bf16x8 al[2][2];
            #pragma unroll
            for (int mi = 0; mi < 2; ++mi) {
                al[mi][0] = *(const bf16x8*)(sl_base + arow + mi * 1024 + ck0);
                al[mi][1] = *(const bf16x8*)(sl_base + arow + mi * 1024 + ck1);
            }
            __builtin_amdgcn_s_setprio(1);
            #pragma unroll
            for (int c = 0; c < 2; ++c)
                #pragma unroll
                for (int mi = 0; mi < 2; ++mi)
                    acc[mi] = __builtin_amdgcn_mfma_f32_32x32x16_bf16(
                        al[mi][c], bh[c], acc[mi], 0, 0, 0);
            __builtin_amdgcn_s_setprio(0);
        }
    }
    #undef STAGE2

    const int ecol = n0 + w * 32 + lane31;
    const float bv = bias[ecol];
    #pragma unroll
    for (int mi = 0; mi < 2; ++mi) {
        #pragma unroll
        for (int r = 0; r < 16; ++r) {
            const int row = m0 + mi * 32 + (r & 3) + 8 * (r >> 2) + 4 * ksel;
            dst[(size_t)row * 1024 + ecol] = acc[mi][r] + bv;
        }
    }
}

// ---------------------------------------------------------------------------
// Partial KV = K_feat^T V and ksum, per (b,h), 16-way N split.
// ---------------------------------------------------------------------------
__global__ __launch_bounds__(256)
void kv_partial_kernel(const float* __restrict__ QKV, float* __restrict__ KVp)
{
    const int bh = blockIdx.x;
    const int s  = blockIdx.y;
    const int b  = bh >> 4;
    const int h  = bh & 15;
    const int t  = threadIdx.x;

    __shared__ float ks[4][68];
    __shared__ float vs[4][68];

    const int d0 = (t >> 4) * 4;
    const int e0 = (t & 15) * 4;

    float acc[4][4];
    #pragma unroll
    for (int i = 0; i < 4; ++i)
        #pragma unroll
        for (int j = 0; j < 4; ++j) acc[i][j] = 0.f;
    float acc_ks[4] = {0.f, 0.f, 0.f, 0.f};

    const int lrow = t >> 6;
    const int lcol = t & 63;
    const size_t kbase = (size_t)b * N_SEQ * 3072 + 1024 + h * 64 + lcol;
    const size_t vbase = (size_t)b * N_SEQ * 3072 + 2048 + h * 64 + lcol;

    for (int it = 0; it < 32; ++it) {
        const int n0 = s * 128 + it * 4;
        const float kval = QKV[kbase + (size_t)(n0 + lrow) * 3072];
        const float vval = QKV[vbase + (size_t)(n0 + lrow) * 3072];
        __syncthreads();
        ks[lrow][lcol] = kval;
        vs[lrow][lcol] = vval;
        __syncthreads();
        #pragma unroll
        for (int r = 0; r < 4; ++r) {
            const float4 k4 = *(const float4*)&ks[r][d0];
            const float4 v4 = *(const float4*)&vs[r][e0];
            const float ka[4] = {k4.x, k4.y, k4.z, k4.w};
            const float va[4] = {v4.x, v4.y, v4.z, v4.w};
            #pragma unroll
            for (int i = 0; i < 4; ++i)
                #pragma unroll
                for (int j = 0; j < 4; ++j)
                    acc[i][j] += ka[i] * va[j];
            if (e0 == 0) {
                #pragma unroll
                for (int i = 0; i < 4; ++i) acc_ks[i] += ka[i];
            }
        }
    }

    float* outp = KVp + ((size_t)s * 32 + bh) * 4160;
    #pragma unroll
    for (int i = 0; i < 4; ++i) {
        float4 o; o.x = acc[i][0]; o.y = acc[i][1]; o.z = acc[i][2]; o.w = acc[i][3];
        *(float4*)(outp + (d0 + i) * 64 + e0) = o;
    }
    if (e0 == 0) {
        #pragma unroll
        for (int i = 0; i < 4; ++i) outp[4096 + d0 + i] = acc_ks[i];
    }
}

__global__ __launch_bounds__(256)
void kv_reduce_kernel(const float* __restrict__ KVp, float* __restrict__ KVf)
{
    const int idx = blockIdx.x * 256 + threadIdx.x;
    if (idx < 32 * 4160) {
        float s = 0.f;
        #pragma unroll
        for (int i = 0; i < 16; ++i) s += KVp[(size_t)i * (32 * 4160) + idx];
        KVf[idx] = s;
    }
}

// ---------------------------------------------------------------------------
// O1[n, h*64+e] = Z * sum_d q[n,d]*KV[d,e], Z = 1/(q.ksum + 1e-6); bf16 hi/lo out
// ---------------------------------------------------------------------------
__global__ __launch_bounds__(256)
void attn_apply_kernel(const float* __restrict__ QKV, const float* __restrict__ KVf,
                       ushort* __restrict__ O1hi, ushort* __restrict__ O1lo)
{
    const int bh = blockIdx.x;
    const int b = bh >> 4, h = bh & 15;
    const int n0 = blockIdx.y * 16;
    const int t = threadIdx.x;
    const int r  = t >> 4;
    const int e0 = (t & 15) * 4;

    __shared__ float kvs[64][68];
    __shared__ float qs[16][68];
    __shared__ float ksums[64];

    const float* kvb = KVf + (size_t)bh * 4160;
    for (int i = t; i < 4096; i += 256)
        kvs[i >> 6][i & 63] = kvb[i];
    if (t < 64) ksums[t] = kvb[4096 + t];
    {
        const int rr = t >> 4, cc2 = (t & 15) * 4;
        *(float4*)&qs[rr][cc2] =
            *(const float4*)&QKV[(size_t)(b * N_SEQ + n0 + rr) * 3072 + h * 64 + cc2];
    }
    __syncthreads();

    float4 acc = {0.f, 0.f, 0.f, 0.f};
    float accz = 0.f;
    #pragma unroll
    for (int d = 0; d < 64; ++d) {
        const float qv = qs[r][d];
        const float4 kvv = *(const float4*)&kvs[d][e0];
        acc.x += qv * kvv.x; acc.y += qv * kvv.y;
        acc.z += qv * kvv.z; acc.w += qv * kvv.w;
        accz += qv * ksums[d];
    }
    const float Z = 1.f / (accz + 1e-6f);
    const float vv[4] = {acc.x * Z, acc.y * Z, acc.z * Z, acc.w * Z};
    ushort hv[4], lv[4];
    #pragma unroll
    for (int j = 0; j < 4; ++j) {
        hv[j] = f2bf(vv[j]);
        lv[j] = f2bf(vv[j] - bf2f(hv[j]));
    }
    const size_t off = (size_t)(b * N_SEQ + n0 + r) * C_DIM + h * 64 + e0;
    short4v H = {(short)hv[0], (short)hv[1], (short)hv[2], (short)hv[3]};
    short4v L = {(short)lv[0], (short)lv[1], (short)lv[2], (short)lv[3]};
    *(short4v*)&O1hi[off] = H;
    *(short4v*)&O1lo[off] = L;
}

extern "C" void kernel_launch(void* const* d_in, const int* in_sizes, int n_in,
                              void* d_out, int out_size, void* d_ws, size_t ws_size,
                              hipStream_t stream)
{
    const float* x   = (const float*)d_in[0];
    const float* Wq  = (const float*)d_in[1];
    const float* Wkv = (const float*)d_in[2];
    const float* Wo  = (const float*)d_in[3];
    const float* bo  = (const float*)d_in[4];
    float* out = (float*)d_out;

    float* ws   = (float*)d_ws;
    float* QKV  = ws;                                  // 4096*3072 f32
    float* KVp  = QKV + (size_t)M_ROWS * 3072;         // 16*32*4160
    float* KVf  = KVp + (size_t)16 * 32 * 4160;        // 32*4160
    ushort* xhi = (ushort*)(KVf + 32 * 4160);          // 4096*1024 bf16 each
    ushort* xlo = xhi + (size_t)M_ROWS * 1024;
    ushort* Whi = xlo + (size_t)M_ROWS * 1024;         // 3072*1024 (Wq;Wkv)
    ushort* Wlo = Whi + (size_t)3072 * 1024;
    ushort* Wohi = Wlo + (size_t)3072 * 1024;          // 1024*1024
    ushort* Wolo = Wohi + (size_t)1024 * 1024;
    ushort* O1hi = xhi;                                // alias: x dead after GEMM1
    ushort* O1lo = xlo;

    hipFuncSetAttribute((const void*)gemm1_mfma256_kernel,
                        hipFuncAttributeMaxDynamicSharedMemorySize, 131072);

    // 0. split fp32 -> bf16 hi/lo (single launch, 1M groups of 8)
    split_all_kernel<<<dim3(4096), 256, 0, stream>>>(
        x, Wq, Wkv, Wo, xhi, xlo, Whi, Wlo, Wohi, Wolo);

    // 1. fused q/k/v projections + elu+1 on q,k
    gemm1_mfma256_kernel<<<dim3(192), 512, 131072, stream>>>(xhi, xlo, Whi, Wlo, QKV);

    // 2-3. KV = K^T V + ksum (split + deterministic reduce)
    kv_partial_kernel<<<dim3(32, 16), 256, 0, stream>>>(QKV, KVp);
    kv_reduce_kernel<<<dim3((32 * 4160 + 255) / 256), 256, 0, stream>>>(KVp, KVf);

    // 4. O1 = Z * (q @ KV), bf16 hi/lo out
    attn_apply_kernel<<<dim3(32, 128), 256, 0, stream>>>(QKV, KVf, O1hi, O1lo);

    // 5. final projection + bias
    gemm2_mfma_kernel<<<dim3(512), 256, 0, stream>>>(O1hi, O1lo, Wohi, Wolo, bo, out);
}

// Round 5
// 167.785 us; speedup vs baseline: 2.8389x; 1.0442x over previous
//
#include <hip/hip_runtime.h>
#include <math.h>

#define C_DIM 1024
#define B_SZ 2
#define N_SEQ 2048
#define M_ROWS (B_SZ * N_SEQ)   // 4096
#define KDIM 1024
#define SLOT_EL 16384           // ushort elements per 32KB gemm1 slot
#define SLOT2_EL 6144           // ushort elements per 12KB gemm2 slot

typedef float  f32x4   __attribute__((ext_vector_type(4)));
typedef float  f32x16  __attribute__((ext_vector_type(16)));
typedef short  bf16x8  __attribute__((ext_vector_type(8)));
typedef short  short4v __attribute__((ext_vector_type(4)));
typedef short  short8v __attribute__((ext_vector_type(8)));

__device__ __forceinline__ float elu1(float v) {
    return v > 0.f ? v + 1.f : expf(v);
}

__device__ __forceinline__ ushort f2bf(float f) {
    union { float f; unsigned u; } x; x.f = f;
    unsigned r = (x.u + 0x7fffu + ((x.u >> 16) & 1u)) >> 16;  // RNE
    return (ushort)r;
}
__device__ __forceinline__ float bf2f(ushort b) {
    union { unsigned u; float f; } x; x.u = ((unsigned)b) << 16;
    return x.f;
}

#define VMCNT(n) asm volatile("s_waitcnt vmcnt(" #n ")" ::: "memory")
#define LGKM0    do { asm volatile("s_waitcnt lgkmcnt(0)" ::: "memory"); \
                      __builtin_amdgcn_sched_barrier(0); } while (0)
#define BAR      __builtin_amdgcn_s_barrier()
#define SB0      __builtin_amdgcn_sched_barrier(0)

__device__ __forceinline__ void gl16(const ushort* g, ushort* l) {
    __builtin_amdgcn_global_load_lds(
        (const __attribute__((address_space(1))) unsigned int*)g,
        (__attribute__((address_space(3))) unsigned int*)l,
        16, 0, 0);
}

// ---------------------------------------------------------------------------
// fp32 -> bf16 hi/lo split for all 4 inputs in one launch. 8 elems/thread.
// ---------------------------------------------------------------------------
__global__ __launch_bounds__(256)
void split_all_kernel(const float* __restrict__ x, const float* __restrict__ Wq,
                      const float* __restrict__ Wkv, const float* __restrict__ Wo,
                      ushort* __restrict__ xhi, ushort* __restrict__ xlo,
                      ushort* __restrict__ Whi, ushort* __restrict__ Wlo,
                      ushort* __restrict__ Wohi, ushort* __restrict__ Wolo)
{
    const int i = blockIdx.x * 256 + threadIdx.x;   // 0..1048575
    const float* src; ushort* dh; ushort* dl; int off;
    if (i < 524288)        { src = x;   dh = xhi;  dl = xlo;  off = i; }
    else if (i < 655360)   { src = Wq;  dh = Whi;  dl = Wlo;  off = i - 524288; }
    else if (i < 917504)   { src = Wkv; dh = Whi + (1u << 20); dl = Wlo + (1u << 20); off = i - 655360; }
    else                   { src = Wo;  dh = Wohi; dl = Wolo; off = i - 917504; }

    const float4 a = ((const float4*)src)[off * 2];
    const float4 b = ((const float4*)src)[off * 2 + 1];
    const float v[8] = {a.x, a.y, a.z, a.w, b.x, b.y, b.z, b.w};
    ushort hv[8], lv[8];
    #pragma unroll
    for (int j = 0; j < 8; ++j) {
        hv[j] = f2bf(v[j]);
        lv[j] = f2bf(v[j] - bf2f(hv[j]));
    }
    short8v H = {(short)hv[0],(short)hv[1],(short)hv[2],(short)hv[3],
                 (short)hv[4],(short)hv[5],(short)hv[6],(short)hv[7]};
    short8v L = {(short)lv[0],(short)lv[1],(short)lv[2],(short)lv[3],
                 (short)lv[4],(short)lv[5],(short)lv[6],(short)lv[7]};
    *(short8v*)&dh[(size_t)off * 8] = H;
    *(short8v*)&dl[(size_t)off * 8] = L;
}

// ---------------------------------------------------------------------------
// GEMM1: QKV = [x][Wq;Wkv]^T, 3-term split-bf16, 256x256 tile, BK=32,
// mfma_f32_16x16x32_bf16. 8 waves (2M x 4N), wave tile 128x64.
// 6-phase m201-style rhythm per kt: each phase {<=8 ds_read || 2 gl_lds ->
// barrier -> lgkm(0) -> setprio 16 MFMA -> barrier}; counted VMCNT(4) at
// phases 1 (hi slot valid) and 3 (lo slot valid) only; vmcnt(0) at kt=31.
// 4-slot LDS pipeline (128 KB), XOR-swizzled via pre-swizzled global source.
// Grid 192 = 16m x 12n, XCD-chunk swizzled.
// ---------------------------------------------------------------------------
__global__ __launch_bounds__(512, 2)
void gemm1_mfma256_kernel(const ushort* __restrict__ Ahi, const ushort* __restrict__ Alo,
                          const ushort* __restrict__ Bhi, const ushort* __restrict__ Blo,
                          float* __restrict__ dst)
{
    extern __shared__ ushort smem[];   // 4 slots x 16384 ushorts (128 KB)

    const int bid = blockIdx.x;
    const int wg  = (bid & 7) * 24 + (bid >> 3);    // bijective: 192 = 8*24
    const int m0  = (wg / 12) * 256;
    const int n0  = (wg % 12) * 256;

    const int t    = threadIdx.x;
    const int lane = t & 63;
    const int w    = t >> 6;
    const int wr   = w >> 2;       // 0..1
    const int wc   = w & 3;        // 0..3

    // staging: thread t -> row t>>2, LDS chunk t&3 holds global chunk gch
    const int gch     = (t & 3) ^ ((t >> 3) & 3);
    const size_t rowA = (size_t)(m0 + (t >> 2)) * KDIM + gch * 8;
    const size_t rowB = (size_t)(n0 + (t >> 2)) * KDIM + gch * 8;
    const int wl      = w * 512;

    // fragment addressing (16x16x32: row = lane&15, k-chunk = lane>>4)
    const int frow = lane & 15;
    const int cc   = (lane >> 4) ^ ((lane >> 1) & 3);  // swizzled 16B slot
    const int aoff = (wr * 128 + frow) * 32 + cc * 8;
    const int boff = 8192 + (wc * 64 + frow) * 32 + cc * 8;

    f32x4 acc[8][4];
    #pragma unroll
    for (int mi = 0; mi < 8; ++mi)
        #pragma unroll
        for (int nj = 0; nj < 4; ++nj)
            acc[mi][nj] = (f32x4){0.f, 0.f, 0.f, 0.f};

    #define STAGE_A(src, slotp, koff)                                        \
        do {                                                                 \
            ushort* sl_ = (slotp);                                           \
            gl16((src) + rowA + (koff),          sl_ + wl);                  \
            gl16((src) + rowA + 131072 + (koff), sl_ + 4096 + wl);           \
        } while (0)
    #define STAGE_B(src, slotp, koff)                                        \
        do {                                                                 \
            ushort* sl_ = (slotp);                                           \
            gl16((src) + rowB + (koff),          sl_ + 8192 + wl);           \
            gl16((src) + rowB + 131072 + (koff), sl_ + 12288 + wl);          \
        } while (0)

    // prologue: hi(0) then lo(0)  (4 + 4 gl16 in flight)
    STAGE_A(Ahi, smem, 0);
    STAGE_B(Bhi, smem, 0);
    STAGE_A(Alo, smem + SLOT_EL, 0);
    STAGE_B(Blo, smem + SLOT_EL, 0);

    #pragma unroll 1
    for (int kt = 0; kt < 32; ++kt) {
        ushort* sh = smem + ((kt & 1) << 1) * SLOT_EL;   // hi slot (kt)
        ushort* sl = sh + SLOT_EL;                       // lo slot (kt)
        ushort* nh = smem + ((2 * kt + 2) & 3) * SLOT_EL; // hi slot (kt+1)
        ushort* nl = smem + ((2 * kt + 3) & 3) * SLOT_EL; // lo slot (kt+1)
        const int kn = (kt + 1) * 32;

        bf16x8 ah[8], bh[4], bl[4], al[8];

        // ---- ph1: validate hi(kt); reads ah0-3,bh0-3; stage A-hi(kt+1)
        VMCNT(4);
        BAR; SB0;
        #pragma unroll
        for (int mi = 0; mi < 4; ++mi)
            ah[mi] = *(const bf16x8*)(sh + aoff + mi * 512);
        #pragma unroll
        for (int nj = 0; nj < 4; ++nj)
            bh[nj] = *(const bf16x8*)(sh + boff + nj * 512);
        if (kt < 31) STAGE_A(Ahi, nh, kn);
        LGKM0;
        __builtin_amdgcn_s_setprio(1);
        #pragma unroll
        for (int mi = 0; mi < 4; ++mi)
            #pragma unroll
            for (int nj = 0; nj < 4; ++nj)
                acc[mi][nj] = __builtin_amdgcn_mfma_f32_16x16x32_bf16(
                    ah[mi], bh[nj], acc[mi][nj], 0, 0, 0);
        __builtin_amdgcn_s_setprio(0);
        BAR;

        // ---- ph2: reads ah4-7; stage B-hi(kt+1)
        #pragma unroll
        for (int mi = 4; mi < 8; ++mi)
            ah[mi] = *(const bf16x8*)(sh + aoff + mi * 512);
        if (kt < 31) STAGE_B(Bhi, nh, kn);
        BAR;
        LGKM0;
        __builtin_amdgcn_s_setprio(1);
        #pragma unroll
        for (int mi = 4; mi < 8; ++mi)
            #pragma unroll
            for (int nj = 0; nj < 4; ++nj)
                acc[mi][nj] = __builtin_amdgcn_mfma_f32_16x16x32_bf16(
                    ah[mi], bh[nj], acc[mi][nj], 0, 0, 0);
        __builtin_amdgcn_s_setprio(0);
        BAR;

        // ---- ph3: validate lo(kt); reads bl; stage A-lo(kt+1)
        if (kt < 31) { VMCNT(4); } else { VMCNT(0); }
        BAR; SB0;
        #pragma unroll
        for (int nj = 0; nj < 4; ++nj)
            bl[nj] = *(const bf16x8*)(sl + boff + nj * 512);
        if (kt < 31) STAGE_A(Alo, nl, kn);
        LGKM0;
        __builtin_amdgcn_s_setprio(1);
        #pragma unroll
        for (int mi = 0; mi < 4; ++mi)
            #pragma unroll
            for (int nj = 0; nj < 4; ++nj)
                acc[mi][nj] = __builtin_amdgcn_mfma_f32_16x16x32_bf16(
                    ah[mi], bl[nj], acc[mi][nj], 0, 0, 0);
        __builtin_amdgcn_s_setprio(0);
        BAR;

        // ---- ph4: reads al0-3; stage B-lo(kt+1)
        #pragma unroll
        for (int mi = 0; mi < 4; ++mi)
            al[mi] = *(const bf16x8*)(sl + aoff + mi * 512);
        if (kt < 31) STAGE_B(Blo, nl, kn);
        BAR;
        LGKM0;
        __builtin_amdgcn_s_setprio(1);
        #pragma unroll
        for (int mi = 4; mi < 8; ++mi)
            #pragma unroll
            for (int nj = 0; nj < 4; ++nj)
                acc[mi][nj] = __builtin_amdgcn_mfma_f32_16x16x32_bf16(
                    ah[mi], bl[nj], acc[mi][nj], 0, 0, 0);
        __builtin_amdgcn_s_setprio(0);
        BAR;

        // ---- ph5: reads al4-7
        #pragma unroll
        for (int mi = 4; mi < 8; ++mi)
            al[mi] = *(const bf16x8*)(sl + aoff + mi * 512);
        BAR;
        LGKM0;
        __builtin_amdgcn_s_setprio(1);
        #pragma unroll
        for (int mi = 0; mi < 4; ++mi)
            #pragma unroll
            for (int nj = 0; nj < 4; ++nj)
                acc[mi][nj] = __builtin_amdgcn_mfma_f32_16x16x32_bf16(
                    al[mi], bh[nj], acc[mi][nj], 0, 0, 0);
        __builtin_amdgcn_s_setprio(0);
        BAR;

        // ---- ph6: pure MFMA
        __builtin_amdgcn_s_setprio(1);
        #pragma unroll
        for (int mi = 4; mi < 8; ++mi)
            #pragma unroll
            for (int nj = 0; nj < 4; ++nj)
                acc[mi][nj] = __builtin_amdgcn_mfma_f32_16x16x32_bf16(
                    al[mi], bh[nj], acc[mi][nj], 0, 0, 0);
        __builtin_amdgcn_s_setprio(0);
        BAR;
    }
    #undef STAGE_A
    #undef STAGE_B

    // epilogue: D frag col = lane&15, row = (lane>>4)*4 + j
    const int erow  = m0 + wr * 128 + (lane >> 4) * 4;
    const int ecol0 = n0 + wc * 64 + frow;
    #pragma unroll
    for (int mi = 0; mi < 8; ++mi) {
        #pragma unroll
        for (int j = 0; j < 4; ++j) {
            const int row = erow + mi * 16 + j;
            #pragma unroll
            for (int nj = 0; nj < 4; ++nj) {
                const int col = ecol0 + nj * 16;
                float v = acc[mi][nj][j];
                if (col < 2048) v = elu1(v);
                dst[(size_t)row * 3072 + col] = v;
            }
        }
    }
}

// ---------------------------------------------------------------------------
// GEMM2: out = O1 @ Wo^T + bo. 64x128 tile, BK=32, 4 waves, 32x32x16 frags,
// 4-slot hi/lo pipeline, vmcnt(3). Grid 512, 48KB LDS.
// ---------------------------------------------------------------------------
__global__ __launch_bounds__(256, 3)
void gemm2_mfma_kernel(const ushort* __restrict__ Ahi, const ushort* __restrict__ Alo,
                       const ushort* __restrict__ Bhi, const ushort* __restrict__ Blo,
                       const float* __restrict__ bias, float* __restrict__ dst)
{
    __shared__ ushort smem[4 * SLOT2_EL];   // 48 KB

    const int bid = blockIdx.x;
    const int wg  = (bid & 7) * 64 + (bid >> 3);    // bijective: 512 = 8*64
    const int m0  = (wg >> 3) * 64;
    const int n0  = (wg & 7) * 128;

    const int t    = threadIdx.x;
    const int lane = t & 63;
    const int w    = t >> 6;      // 0..3 (N quarters)

    const int gch     = (t & 3) ^ ((t >> 3) & 3);
    const size_t rowA = (size_t)(m0 + (t >> 2)) * KDIM + gch * 8;
    const size_t rowB = (size_t)(n0 + (t >> 2)) * KDIM + gch * 8;
    const int wl      = w * 512;

    const int lane31 = lane & 31;
    const int ksel   = lane >> 5;
    const int swz    = (lane >> 1) & 3;
    const int ck0    = ((0 + ksel) ^ swz) * 8;
    const int ck1    = ((2 + ksel) ^ swz) * 8;
    const int arow   = lane31 * 32;
    const int brow   = 2048 + (w * 32 + lane31) * 32;

    f32x16 acc[2];
    #pragma unroll
    for (int mi = 0; mi < 2; ++mi)
        #pragma unroll
        for (int e = 0; e < 16; ++e)
            acc[mi][e] = 0.f;

    #define STAGE2(srcA, srcB, slotp, koff)                                  \
        do {                                                                 \
            ushort* sl_ = (slotp);                                           \
            gl16((srcA) + rowA + (koff),         sl_ + wl);                  \
            gl16((srcB) + rowB + (koff),         sl_ + 2048 + wl);           \
            gl16((srcB) + rowB + 65536 + (koff), sl_ + 4096 + wl);           \
        } while (0)

    STAGE2(Ahi, Bhi, smem, 0);
    STAGE2(Alo, Blo, smem + SLOT2_EL, 0);

    #pragma unroll 1
    for (int kt = 0; kt < 32; ++kt) {
        ushort* sh_base = smem + ((kt & 1) << 1) * SLOT2_EL;
        ushort* sl_base = sh_base + SLOT2_EL;
        const int koff_next = (kt + 1) * 32;

        VMCNT(3);
        __builtin_amdgcn_s_barrier();
        if (kt < 31)
            STAGE2(Ahi, Bhi, smem + ((2 * kt + 2) & 3) * SLOT2_EL, koff_next);

        bf16x8 ah[2][2], bh[2];
        #pragma unroll
        for (int mi = 0; mi < 2; ++mi) {
            ah[mi][0] = *(const bf16x8*)(sh_base + arow + mi * 1024 + ck0);
            ah[mi][1] = *(const bf16x8*)(sh_base + arow + mi * 1024 + ck1);
        }
        bh[0] = *(const bf16x8*)(sh_base + brow + ck0);
        bh[1] = *(const bf16x8*)(sh_base + brow + ck1);
        __builtin_amdgcn_s_setprio(1);
        #pragma unroll
        for (int c = 0; c < 2; ++c)
            #pragma unroll
            for (int mi = 0; mi < 2; ++mi)
                acc[mi] = __builtin_amdgcn_mfma_f32_32x32x16_bf16(
                    ah[mi][c], bh[c], acc[mi], 0, 0, 0);
        __builtin_amdgcn_s_setprio(0);

        if (kt < 31) { VMCNT(3); } else { VMCNT(0); }
        __builtin_amdgcn_s_barrier();
        if (kt < 31)
            STAGE2(Alo, Blo, smem + ((2 * kt + 3) & 3) * SLOT2_EL, koff_next);

        {
            bf16x8 bl[2];
            bl[0] = *(const bf16x8*)(sl_base + brow + ck0);
            bl[1] = *(const bf16x8*)(sl_base + brow + ck1);
            __builtin_amdgcn_s_setprio(1);
            #pragma unroll
            for (int c = 0; c < 2; ++c)
                #pragma unroll
                for (int mi = 0; mi < 2; ++mi)
                    acc[mi] = __builtin_amdgcn_mfma_f32_32x32x16_bf16(
                        ah[mi][c], bl[c], acc[mi], 0, 0, 0);
            __builtin_amdgcn_s_setprio(0);
            bf16x8 al[2][2];
            #pragma unroll
            for (int mi = 0; mi < 2; ++mi) {
                al[mi][0] = *(const bf16x8*)(sl_base + arow + mi * 1024 + ck0);
                al[mi][1] = *(const bf16x8*)(sl_base + arow + mi * 1024 + ck1);
            }
            __builtin_amdgcn_s_setprio(1);
            #pragma unroll
            for (int c = 0; c < 2; ++c)
                #pragma unroll
                for (int mi = 0; mi < 2; ++mi)
                    acc[mi] = __builtin_amdgcn_mfma_f32_32x32x16_bf16(
                        al[mi][c], bh[c], acc[mi], 0, 0, 0);
            __builtin_amdgcn_s_setprio(0);
        }
    }
    #undef STAGE2

    const int ecol = n0 + w * 32 + lane31;
    const float bv = bias[ecol];
    #pragma unroll
    for (int mi = 0; mi < 2; ++mi) {
        #pragma unroll
        for (int r = 0; r < 16; ++r) {
            const int row = m0 + mi * 32 + (r & 3) + 8 * (r >> 2) + 4 * ksel;
            dst[(size_t)row * 1024 + ecol] = acc[mi][r] + bv;
        }
    }
}

// ---------------------------------------------------------------------------
// Partial KV = K_feat^T V and ksum, per (b,h), 16-way N split.
// ---------------------------------------------------------------------------
__global__ __launch_bounds__(256)
void kv_partial_kernel(const float* __restrict__ QKV, float* __restrict__ KVp)
{
    const int bh = blockIdx.x;
    const int s  = blockIdx.y;
    const int b  = bh >> 4;
    const int h  = bh & 15;
    const int t  = threadIdx.x;

    __shared__ float ks[4][68];
    __shared__ float vs[4][68];

    const int d0 = (t >> 4) * 4;
    const int e0 = (t & 15) * 4;

    float acc[4][4];
    #pragma unroll
    for (int i = 0; i < 4; ++i)
        #pragma unroll
        for (int j = 0; j < 4; ++j) acc[i][j] = 0.f;
    float acc_ks[4] = {0.f, 0.f, 0.f, 0.f};

    const int lrow = t >> 6;
    const int lcol = t & 63;
    const size_t kbase = (size_t)b * N_SEQ * 3072 + 1024 + h * 64 + lcol;
    const size_t vbase = (size_t)b * N_SEQ * 3072 + 2048 + h * 64 + lcol;

    for (int it = 0; it < 32; ++it) {
        const int n0 = s * 128 + it * 4;
        const float kval = QKV[kbase + (size_t)(n0 + lrow) * 3072];
        const float vval = QKV[vbase + (size_t)(n0 + lrow) * 3072];
        __syncthreads();
        ks[lrow][lcol] = kval;
        vs[lrow][lcol] = vval;
        __syncthreads();
        #pragma unroll
        for (int r = 0; r < 4; ++r) {
            const float4 k4 = *(const float4*)&ks[r][d0];
            const float4 v4 = *(const float4*)&vs[r][e0];
            const float ka[4] = {k4.x, k4.y, k4.z, k4.w};
            const float va[4] = {v4.x, v4.y, v4.z, v4.w};
            #pragma unroll
            for (int i = 0; i < 4; ++i)
                #pragma unroll
                for (int j = 0; j < 4; ++j)
                    acc[i][j] += ka[i] * va[j];
            if (e0 == 0) {
                #pragma unroll
                for (int i = 0; i < 4; ++i) acc_ks[i] += ka[i];
            }
        }
    }

    float* outp = KVp + ((size_t)s * 32 + bh) * 4160;
    #pragma unroll
    for (int i = 0; i < 4; ++i) {
        float4 o; o.x = acc[i][0]; o.y = acc[i][1]; o.z = acc[i][2]; o.w = acc[i][3];
        *(float4*)(outp + (d0 + i) * 64 + e0) = o;
    }
    if (e0 == 0) {
        #pragma unroll
        for (int i = 0; i < 4; ++i) outp[4096 + d0 + i] = acc_ks[i];
    }
}

__global__ __launch_bounds__(256)
void kv_reduce_kernel(const float* __restrict__ KVp, float* __restrict__ KVf)
{
    const int idx = blockIdx.x * 256 + threadIdx.x;
    if (idx < 32 * 4160) {
        float s = 0.f;
        #pragma unroll
        for (int i = 0; i < 16; ++i) s += KVp[(size_t)i * (32 * 4160) + idx];
        KVf[idx] = s;
    }
}

// ---------------------------------------------------------------------------
// O1[n, h*64+e] = Z * sum_d q[n,d]*KV[d,e], Z = 1/(q.ksum + 1e-6); bf16 hi/lo out
// ---------------------------------------------------------------------------
__global__ __launch_bounds__(256)
void attn_apply_kernel(const float* __restrict__ QKV, const float* __restrict__ KVf,
                       ushort* __restrict__ O1hi, ushort* __restrict__ O1lo)
{
    const int bh = blockIdx.x;
    const int b = bh >> 4, h = bh & 15;
    const int n0 = blockIdx.y * 16;
    const int t = threadIdx.x;
    const int r  = t >> 4;
    const int e0 = (t & 15) * 4;

    __shared__ float kvs[64][68];
    __shared__ float qs[16][68];
    __shared__ float ksums[64];

    const float* kvb = KVf + (size_t)bh * 4160;
    for (int i = t; i < 4096; i += 256)
        kvs[i >> 6][i & 63] = kvb[i];
    if (t < 64) ksums[t] = kvb[4096 + t];
    {
        const int rr = t >> 4, cc2 = (t & 15) * 4;
        *(float4*)&qs[rr][cc2] =
            *(const float4*)&QKV[(size_t)(b * N_SEQ + n0 + rr) * 3072 + h * 64 + cc2];
    }
    __syncthreads();

    float4 acc = {0.f, 0.f, 0.f, 0.f};
    float accz = 0.f;
    #pragma unroll
    for (int d = 0; d < 64; ++d) {
        const float qv = qs[r][d];
        const float4 kvv = *(const float4*)&kvs[d][e0];
        acc.x += qv * kvv.x; acc.y += qv * kvv.y;
        acc.z += qv * kvv.z; acc.w += qv * kvv.w;
        accz += qv * ksums[d];
    }
    const float Z = 1.f / (accz + 1e-6f);
    const float vv[4] = {acc.x * Z, acc.y * Z, acc.z * Z, acc.w * Z};
    ushort hv[4], lv[4];
    #pragma unroll
    for (int j = 0; j < 4; ++j) {
        hv[j] = f2bf(vv[j]);
        lv[j] = f2bf(vv[j] - bf2f(hv[j]));
    }
    const size_t off = (size_t)(b * N_SEQ + n0 + r) * C_DIM + h * 64 + e0;
    short4v H = {(short)hv[0], (short)hv[1], (short)hv[2], (short)hv[3]};
    short4v L = {(short)lv[0], (short)lv[1], (short)lv[2], (short)lv[3]};
    *(short4v*)&O1hi[off] = H;
    *(short4v*)&O1lo[off] = L;
}

extern "C" void kernel_launch(void* const* d_in, const int* in_sizes, int n_in,
                              void* d_out, int out_size, void* d_ws, size_t ws_size,
                              hipStream_t stream)
{
    const float* x   = (const float*)d_in[0];
    const float* Wq  = (const float*)d_in[1];
    const float* Wkv = (const float*)d_in[2];
    const float* Wo  = (const float*)d_in[3];
    const float* bo  = (const float*)d_in[4];
    float* out = (float*)d_out;

    float* ws   = (float*)d_ws;
    float* QKV  = ws;                                  // 4096*3072 f32
    float* KVp  = QKV + (size_t)M_ROWS * 3072;         // 16*32*4160
    float* KVf  = KVp + (size_t)16 * 32 * 4160;        // 32*4160
    ushort* xhi = (ushort*)(KVf + 32 * 4160);          // 4096*1024 bf16 each
    ushort* xlo = xhi + (size_t)M_ROWS * 1024;
    ushort* Whi = xlo + (size_t)M_ROWS * 1024;         // 3072*1024 (Wq;Wkv)
    ushort* Wlo = Whi + (size_t)3072 * 1024;
    ushort* Wohi = Wlo + (size_t)3072 * 1024;          // 1024*1024
    ushort* Wolo = Wohi + (size_t)1024 * 1024;
    ushort* O1hi = xhi;                                // alias: x dead after GEMM1
    ushort* O1lo = xlo;

    hipFuncSetAttribute((const void*)gemm1_mfma256_kernel,
                        hipFuncAttributeMaxDynamicSharedMemorySize, 131072);

    // 0. split fp32 -> bf16 hi/lo
    split_all_kernel<<<dim3(4096), 256, 0, stream>>>(
        x, Wq, Wkv, Wo, xhi, xlo, Whi, Wlo, Wohi, Wolo);

    // 1. fused q/k/v projections + elu+1 on q,k
    gemm1_mfma256_kernel<<<dim3(192), 512, 131072, stream>>>(xhi, xlo, Whi, Wlo, QKV);

    // 2-3. KV = K^T V + ksum (split + deterministic reduce)
    kv_partial_kernel<<<dim3(32, 16), 256, 0, stream>>>(QKV, KVp);
    kv_reduce_kernel<<<dim3((32 * 4160 + 255) / 256), 256, 0, stream>>>(KVp, KVf);

    // 4. O1 = Z * (q @ KV), bf16 hi/lo out
    attn_apply_kernel<<<dim3(32, 128), 256, 0, stream>>>(QKV, KVf, O1hi, O1lo);

    // 5. final projection + bias
    gemm2_mfma_kernel<<<dim3(512), 256, 0, stream>>>(O1hi, O1lo, Wohi, Wolo, bo, out);
}

// Round 6
// 160.196 us; speedup vs baseline: 2.9734x; 1.0474x over previous
//
#include <hip/hip_runtime.h>
#include <math.h>

#define C_DIM 1024
#define B_SZ 2
#define N_SEQ 2048
#define M_ROWS (B_SZ * N_SEQ)   // 4096
#define KDIM 1024
#define SLOT_EL 16384           // ushort elements per 32KB gemm1 slot
#define SLOT2_EL 6144           // ushort elements per 12KB gemm2 slot

typedef float  f32x4   __attribute__((ext_vector_type(4)));
typedef float  f32x16  __attribute__((ext_vector_type(16)));
typedef short  bf16x8  __attribute__((ext_vector_type(8)));
typedef short  short4v __attribute__((ext_vector_type(4)));
typedef short  short8v __attribute__((ext_vector_type(8)));

__device__ __forceinline__ float elu1(float v) {
    return v > 0.f ? v + 1.f : expf(v);
}

__device__ __forceinline__ ushort f2bf(float f) {
    union { float f; unsigned u; } x; x.f = f;
    unsigned r = (x.u + 0x7fffu + ((x.u >> 16) & 1u)) >> 16;  // RNE
    return (ushort)r;
}
__device__ __forceinline__ float bf2f(ushort b) {
    union { unsigned u; float f; } x; x.u = ((unsigned)b) << 16;
    return x.f;
}

#define VMCNT(n) asm volatile("s_waitcnt vmcnt(" #n ")" ::: "memory")
#define LGKM0    do { asm volatile("s_waitcnt lgkmcnt(0)" ::: "memory"); \
                      __builtin_amdgcn_sched_barrier(0); } while (0)
#define BAR      __builtin_amdgcn_s_barrier()
#define SB0      __builtin_amdgcn_sched_barrier(0)

__device__ __forceinline__ void gl16(const ushort* g, ushort* l) {
    __builtin_amdgcn_global_load_lds(
        (const __attribute__((address_space(1))) unsigned int*)g,
        (__attribute__((address_space(3))) unsigned int*)l,
        16, 0, 0);
}

// ---------------------------------------------------------------------------
// fp32 -> bf16 hi/lo split for all 4 inputs in one launch. 8 elems/thread.
// ---------------------------------------------------------------------------
__global__ __launch_bounds__(256)
void split_all_kernel(const float* __restrict__ x, const float* __restrict__ Wq,
                      const float* __restrict__ Wkv, const float* __restrict__ Wo,
                      ushort* __restrict__ xhi, ushort* __restrict__ xlo,
                      ushort* __restrict__ Whi, ushort* __restrict__ Wlo,
                      ushort* __restrict__ Wohi, ushort* __restrict__ Wolo)
{
    const int i = blockIdx.x * 256 + threadIdx.x;   // 0..1048575
    const float* src; ushort* dh; ushort* dl; int off;
    if (i < 524288)        { src = x;   dh = xhi;  dl = xlo;  off = i; }
    else if (i < 655360)   { src = Wq;  dh = Whi;  dl = Wlo;  off = i - 524288; }
    else if (i < 917504)   { src = Wkv; dh = Whi + (1u << 20); dl = Wlo + (1u << 20); off = i - 655360; }
    else                   { src = Wo;  dh = Wohi; dl = Wolo; off = i - 917504; }

    const float4 a = ((const float4*)src)[off * 2];
    const float4 b = ((const float4*)src)[off * 2 + 1];
    const float v[8] = {a.x, a.y, a.z, a.w, b.x, b.y, b.z, b.w};
    ushort hv[8], lv[8];
    #pragma unroll
    for (int j = 0; j < 8; ++j) {
        hv[j] = f2bf(v[j]);
        lv[j] = f2bf(v[j] - bf2f(hv[j]));
    }
    short8v H = {(short)hv[0],(short)hv[1],(short)hv[2],(short)hv[3],
                 (short)hv[4],(short)hv[5],(short)hv[6],(short)hv[7]};
    short8v L = {(short)lv[0],(short)lv[1],(short)lv[2],(short)lv[3],
                 (short)lv[4],(short)lv[5],(short)lv[6],(short)lv[7]};
    *(short8v*)&dh[(size_t)off * 8] = H;
    *(short8v*)&dl[(size_t)off * 8] = L;
}

// ---------------------------------------------------------------------------
// GEMM1: QKV = [x][Wq;Wkv]^T, 3-term split-bf16, 256x192 tile, BK=32,
// mfma_f32_16x16x32_bf16. 8 waves (2M x 4N), wave tile 128x48.
// Grid 256 = 16m x 16n -> EXACTLY 1 block/CU (full fill). 6-phase rhythm,
// 12 MFMA/phase, counted VMCNT(4) at phases 1/3, 4-slot 128KB LDS pipeline,
// XOR-swizzled via pre-swizzled global_load_lds source. B LDS region padded
// to 256 rows (rows 192..255 staged as clamped dups, never read) so every
// unit is a uniform 4 gl16/thread.
// ---------------------------------------------------------------------------
__global__ __launch_bounds__(512, 2)
void gemm1_mfma256_kernel(const ushort* __restrict__ Ahi, const ushort* __restrict__ Alo,
                          const ushort* __restrict__ Bhi, const ushort* __restrict__ Blo,
                          float* __restrict__ dst)
{
    extern __shared__ ushort smem[];   // 4 slots x 16384 ushorts (128 KB)

    const int bid = blockIdx.x;
    const int wg  = (bid & 7) * 32 + (bid >> 3);    // bijective: 256 = 8*32
    const int m0  = (wg >> 4) * 256;
    const int n0  = (wg & 15) * 192;

    const int t    = threadIdx.x;
    const int lane = t & 63;
    const int w    = t >> 6;
    const int wr   = w >> 2;       // 0..1
    const int wc   = w & 3;        // 0..3

    // staging: thread t -> row t>>2, LDS chunk t&3 holds global chunk gch
    const int gch     = (t & 3) ^ ((t >> 3) & 3);
    const size_t rowA  = (size_t)(m0 + (t >> 2)) * KDIM + gch * 8;          // A rows 0..127
    const size_t rowA2 = rowA + (size_t)128 * KDIM;                          // A rows 128..255
    const size_t rowB  = (size_t)(n0 + (t >> 2)) * KDIM + gch * 8;          // B rows 0..127
    const int    bclmp = (n0 + (t >> 2) + 128 < 3072) ? (n0 + (t >> 2) + 128) : 3071;
    const size_t rowB2 = (size_t)bclmp * KDIM + gch * 8;                     // B rows 128..191 (+dups)
    const int wl      = w * 512;

    // fragment addressing (16x16x32: row = lane&15, k-chunk = lane>>4)
    const int frow = lane & 15;
    const int cc   = (lane >> 4) ^ ((lane >> 1) & 3);  // swizzled 16B slot
    const int aoff = (wr * 128 + frow) * 32 + cc * 8;
    const int boff = 8192 + (wc * 48 + frow) * 32 + cc * 8;

    f32x4 acc[8][3];
    #pragma unroll
    for (int mi = 0; mi < 8; ++mi)
        #pragma unroll
        for (int nj = 0; nj < 3; ++nj)
            acc[mi][nj] = (f32x4){0.f, 0.f, 0.f, 0.f};

    #define STAGE_A(src, slotp, koff)                                        \
        do {                                                                 \
            ushort* sl_ = (slotp);                                           \
            gl16((src) + rowA  + (koff), sl_ + wl);                          \
            gl16((src) + rowA2 + (koff), sl_ + 4096 + wl);                   \
        } while (0)
    #define STAGE_B(src, slotp, koff)                                        \
        do {                                                                 \
            ushort* sl_ = (slotp);                                           \
            gl16((src) + rowB  + (koff), sl_ + 8192 + wl);                   \
            gl16((src) + rowB2 + (koff), sl_ + 12288 + wl);                  \
        } while (0)

    // prologue: hi(0) then lo(0)  (4 + 4 gl16 in flight)
    STAGE_A(Ahi, smem, 0);
    STAGE_B(Bhi, smem, 0);
    STAGE_A(Alo, smem + SLOT_EL, 0);
    STAGE_B(Blo, smem + SLOT_EL, 0);

    #pragma unroll 1
    for (int kt = 0; kt < 32; ++kt) {
        ushort* sh = smem + ((kt & 1) << 1) * SLOT_EL;    // hi slot (kt)
        ushort* sl = sh + SLOT_EL;                        // lo slot (kt)
        ushort* nh = smem + ((2 * kt + 2) & 3) * SLOT_EL; // hi slot (kt+1)
        ushort* nl = smem + ((2 * kt + 3) & 3) * SLOT_EL; // lo slot (kt+1)
        const int kn = (kt + 1) * 32;

        bf16x8 ah[8], bh[3], bl[3], al[8];

        // ---- ph1: validate hi(kt); reads ah0-3,bh; stage A-hi(kt+1)
        VMCNT(4);
        BAR; SB0;
        #pragma unroll
        for (int mi = 0; mi < 4; ++mi)
            ah[mi] = *(const bf16x8*)(sh + aoff + mi * 512);
        #pragma unroll
        for (int nj = 0; nj < 3; ++nj)
            bh[nj] = *(const bf16x8*)(sh + boff + nj * 512);
        if (kt < 31) STAGE_A(Ahi, nh, kn);
        LGKM0;
        __builtin_amdgcn_s_setprio(1);
        #pragma unroll
        for (int mi = 0; mi < 4; ++mi)
            #pragma unroll
            for (int nj = 0; nj < 3; ++nj)
                acc[mi][nj] = __builtin_amdgcn_mfma_f32_16x16x32_bf16(
                    ah[mi], bh[nj], acc[mi][nj], 0, 0, 0);
        __builtin_amdgcn_s_setprio(0);
        BAR;

        // ---- ph2: reads ah4-7; stage B-hi(kt+1)
        #pragma unroll
        for (int mi = 4; mi < 8; ++mi)
            ah[mi] = *(const bf16x8*)(sh + aoff + mi * 512);
        if (kt < 31) STAGE_B(Bhi, nh, kn);
        BAR;
        LGKM0;
        __builtin_amdgcn_s_setprio(1);
        #pragma unroll
        for (int mi = 4; mi < 8; ++mi)
            #pragma unroll
            for (int nj = 0; nj < 3; ++nj)
                acc[mi][nj] = __builtin_amdgcn_mfma_f32_16x16x32_bf16(
                    ah[mi], bh[nj], acc[mi][nj], 0, 0, 0);
        __builtin_amdgcn_s_setprio(0);
        BAR;

        // ---- ph3: validate lo(kt); reads bl; stage A-lo(kt+1)
        if (kt < 31) { VMCNT(4); } else { VMCNT(0); }
        BAR; SB0;
        #pragma unroll
        for (int nj = 0; nj < 3; ++nj)
            bl[nj] = *(const bf16x8*)(sl + boff + nj * 512);
        if (kt < 31) STAGE_A(Alo, nl, kn);
        LGKM0;
        __builtin_amdgcn_s_setprio(1);
        #pragma unroll
        for (int mi = 0; mi < 4; ++mi)
            #pragma unroll
            for (int nj = 0; nj < 3; ++nj)
                acc[mi][nj] = __builtin_amdgcn_mfma_f32_16x16x32_bf16(
                    ah[mi], bl[nj], acc[mi][nj], 0, 0, 0);
        __builtin_amdgcn_s_setprio(0);
        BAR;

        // ---- ph4: reads al0-3; stage B-lo(kt+1)
        #pragma unroll
        for (int mi = 0; mi < 4; ++mi)
            al[mi] = *(const bf16x8*)(sl + aoff + mi * 512);
        if (kt < 31) STAGE_B(Blo, nl, kn);
        BAR;
        LGKM0;
        __builtin_amdgcn_s_setprio(1);
        #pragma unroll
        for (int mi = 4; mi < 8; ++mi)
            #pragma unroll
            for (int nj = 0; nj < 3; ++nj)
                acc[mi][nj] = __builtin_amdgcn_mfma_f32_16x16x32_bf16(
                    ah[mi], bl[nj], acc[mi][nj], 0, 0, 0);
        __builtin_amdgcn_s_setprio(0);
        BAR;

        // ---- ph5: reads al4-7
        #pragma unroll
        for (int mi = 4; mi < 8; ++mi)
            al[mi] = *(const bf16x8*)(sl + aoff + mi * 512);
        BAR;
        LGKM0;
        __builtin_amdgcn_s_setprio(1);
        #pragma unroll
        for (int mi = 0; mi < 4; ++mi)
            #pragma unroll
            for (int nj = 0; nj < 3; ++nj)
                acc[mi][nj] = __builtin_amdgcn_mfma_f32_16x16x32_bf16(
                    al[mi], bh[nj], acc[mi][nj], 0, 0, 0);
        __builtin_amdgcn_s_setprio(0);
        BAR;

        // ---- ph6: pure MFMA
        __builtin_amdgcn_s_setprio(1);
        #pragma unroll
        for (int mi = 4; mi < 8; ++mi)
            #pragma unroll
            for (int nj = 0; nj < 3; ++nj)
                acc[mi][nj] = __builtin_amdgcn_mfma_f32_16x16x32_bf16(
                    al[mi], bh[nj], acc[mi][nj], 0, 0, 0);
        __builtin_amdgcn_s_setprio(0);
        BAR;
    }
    #undef STAGE_A
    #undef STAGE_B

    // epilogue: D frag col = lane&15, row = (lane>>4)*4 + j
    const int erow  = m0 + wr * 128 + (lane >> 4) * 4;
    const int ecol0 = n0 + wc * 48 + frow;
    #pragma unroll
    for (int mi = 0; mi < 8; ++mi) {
        #pragma unroll
        for (int j = 0; j < 4; ++j) {
            const int row = erow + mi * 16 + j;
            #pragma unroll
            for (int nj = 0; nj < 3; ++nj) {
                const int col = ecol0 + nj * 16;
                float v = acc[mi][nj][j];
                if (col < 2048) v = elu1(v);
                dst[(size_t)row * 3072 + col] = v;
            }
        }
    }
}

// ---------------------------------------------------------------------------
// GEMM2: out = O1 @ Wo^T + bo. 64x128 tile, BK=32, 4 waves, 32x32x16 frags,
// 4-slot hi/lo pipeline, vmcnt(3). Grid 512, 48KB LDS.
// ---------------------------------------------------------------------------
__global__ __launch_bounds__(256, 3)
void gemm2_mfma_kernel(const ushort* __restrict__ Ahi, const ushort* __restrict__ Alo,
                       const ushort* __restrict__ Bhi, const ushort* __restrict__ Blo,
                       const float* __restrict__ bias, float* __restrict__ dst)
{
    __shared__ ushort smem[4 * SLOT2_EL];   // 48 KB

    const int bid = blockIdx.x;
    const int wg  = (bid & 7) * 64 + (bid >> 3);    // bijective: 512 = 8*64
    const int m0  = (wg >> 3) * 64;
    const int n0  = (wg & 7) * 128;

    const int t    = threadIdx.x;
    const int lane = t & 63;
    const int w    = t >> 6;      // 0..3 (N quarters)

    const int gch     = (t & 3) ^ ((t >> 3) & 3);
    const size_t rowA = (size_t)(m0 + (t >> 2)) * KDIM + gch * 8;
    const size_t rowB = (size_t)(n0 + (t >> 2)) * KDIM + gch * 8;
    const int wl      = w * 512;

    const int lane31 = lane & 31;
    const int ksel   = lane >> 5;
    const int swz    = (lane >> 1) & 3;
    const int ck0    = ((0 + ksel) ^ swz) * 8;
    const int ck1    = ((2 + ksel) ^ swz) * 8;
    const int arow   = lane31 * 32;
    const int brow   = 2048 + (w * 32 + lane31) * 32;

    f32x16 acc[2];
    #pragma unroll
    for (int mi = 0; mi < 2; ++mi)
        #pragma unroll
        for (int e = 0; e < 16; ++e)
            acc[mi][e] = 0.f;

    #define STAGE2(srcA, srcB, slotp, koff)                                  \
        do {                                                                 \
            ushort* sl_ = (slotp);                                           \
            gl16((srcA) + rowA + (koff),         sl_ + wl);                  \
            gl16((srcB) + rowB + (koff),         sl_ + 2048 + wl);           \
            gl16((srcB) + rowB + 65536 + (koff), sl_ + 4096 + wl);           \
        } while (0)

    STAGE2(Ahi, Bhi, smem, 0);
    STAGE2(Alo, Blo, smem + SLOT2_EL, 0);

    #pragma unroll 1
    for (int kt = 0; kt < 32; ++kt) {
        ushort* sh_base = smem + ((kt & 1) << 1) * SLOT2_EL;
        ushort* sl_base = sh_base + SLOT2_EL;
        const int koff_next = (kt + 1) * 32;

        VMCNT(3);
        __builtin_amdgcn_s_barrier();
        if (kt < 31)
            STAGE2(Ahi, Bhi, smem + ((2 * kt + 2) & 3) * SLOT2_EL, koff_next);

        bf16x8 ah[2][2], bh[2];
        #pragma unroll
        for (int mi = 0; mi < 2; ++mi) {
            ah[mi][0] = *(const bf16x8*)(sh_base + arow + mi * 1024 + ck0);
            ah[mi][1] = *(const bf16x8*)(sh_base + arow + mi * 1024 + ck1);
        }
        bh[0] = *(const bf16x8*)(sh_base + brow + ck0);
        bh[1] = *(const bf16x8*)(sh_base + brow + ck1);
        __builtin_amdgcn_s_setprio(1);
        #pragma unroll
        for (int c = 0; c < 2; ++c)
            #pragma unroll
            for (int mi = 0; mi < 2; ++mi)
                acc[mi] = __builtin_amdgcn_mfma_f32_32x32x16_bf16(
                    ah[mi][c], bh[c], acc[mi], 0, 0, 0);
        __builtin_amdgcn_s_setprio(0);

        if (kt < 31) { VMCNT(3); } else { VMCNT(0); }
        __builtin_amdgcn_s_barrier();
        if (kt < 31)
            STAGE2(Alo, Blo, smem + ((2 * kt + 3) & 3) * SLOT2_EL, koff_next);

        {
            bf16x8 bl[2];
            bl[0] = *(const bf16x8*)(sl_base + brow + ck0);
            bl[1] = *(const bf16x8*)(sl_base + brow + ck1);
            __builtin_amdgcn_s_setprio(1);
            #pragma unroll
            for (int c = 0; c < 2; ++c)
                #pragma unroll
                for (int mi = 0; mi < 2; ++mi)
                    acc[mi] = __builtin_amdgcn_mfma_f32_32x32x16_bf16(
                        ah[mi][c], bl[c], acc[mi], 0, 0, 0);
            __builtin_amdgcn_s_setprio(0);
            bf16x8 al[2][2];
            #pragma unroll
            for (int mi = 0; mi < 2; ++mi) {
                al[mi][0] = *(const bf16x8*)(sl_base + arow + mi * 1024 + ck0);
                al[mi][1] = *(const bf16x8*)(sl_base + arow + mi * 1024 + ck1);
            }
            __builtin_amdgcn_s_setprio(1);
            #pragma unroll
            for (int c = 0; c < 2; ++c)
                #pragma unroll
                for (int mi = 0; mi < 2; ++mi)
                    acc[mi] = __builtin_amdgcn_mfma_f32_32x32x16_bf16(
                        al[mi][c], bh[c], acc[mi], 0, 0, 0);
            __builtin_amdgcn_s_setprio(0);
        }
    }
    #undef STAGE2

    const int ecol = n0 + w * 32 + lane31;
    const float bv = bias[ecol];
    #pragma unroll
    for (int mi = 0; mi < 2; ++mi) {
        #pragma unroll
        for (int r = 0; r < 16; ++r) {
            const int row = m0 + mi * 32 + (r & 3) + 8 * (r >> 2) + 4 * ksel;
            dst[(size_t)row * 1024 + ecol] = acc[mi][r] + bv;
        }
    }
}

// ---------------------------------------------------------------------------
// Partial KV = K_feat^T V and ksum, per (b,h), 16-way N split.
// ---------------------------------------------------------------------------
__global__ __launch_bounds__(256)
void kv_partial_kernel(const float* __restrict__ QKV, float* __restrict__ KVp)
{
    const int bh = blockIdx.x;
    const int s  = blockIdx.y;
    const int b  = bh >> 4;
    const int h  = bh & 15;
    const int t  = threadIdx.x;

    __shared__ float ks[4][68];
    __shared__ float vs[4][68];

    const int d0 = (t >> 4) * 4;
    const int e0 = (t & 15) * 4;

    float acc[4][4];
    #pragma unroll
    for (int i = 0; i < 4; ++i)
        #pragma unroll
        for (int j = 0; j < 4; ++j) acc[i][j] = 0.f;
    float acc_ks[4] = {0.f, 0.f, 0.f, 0.f};

    const int lrow = t >> 6;
    const int lcol = t & 63;
    const size_t kbase = (size_t)b * N_SEQ * 3072 + 1024 + h * 64 + lcol;
    const size_t vbase = (size_t)b * N_SEQ * 3072 + 2048 + h * 64 + lcol;

    for (int it = 0; it < 32; ++it) {
        const int n0 = s * 128 + it * 4;
        const float kval = QKV[kbase + (size_t)(n0 + lrow) * 3072];
        const float vval = QKV[vbase + (size_t)(n0 + lrow) * 3072];
        __syncthreads();
        ks[lrow][lcol] = kval;
        vs[lrow][lcol] = vval;
        __syncthreads();
        #pragma unroll
        for (int r = 0; r < 4; ++r) {
            const float4 k4 = *(const float4*)&ks[r][d0];
            const float4 v4 = *(const float4*)&vs[r][e0];
            const float ka[4] = {k4.x, k4.y, k4.z, k4.w};
            const float va[4] = {v4.x, v4.y, v4.z, v4.w};
            #pragma unroll
            for (int i = 0; i < 4; ++i)
                #pragma unroll
                for (int j = 0; j < 4; ++j)
                    acc[i][j] += ka[i] * va[j];
            if (e0 == 0) {
                #pragma unroll
                for (int i = 0; i < 4; ++i) acc_ks[i] += ka[i];
            }
        }
    }

    float* outp = KVp + ((size_t)s * 32 + bh) * 4160;
    #pragma unroll
    for (int i = 0; i < 4; ++i) {
        float4 o; o.x = acc[i][0]; o.y = acc[i][1]; o.z = acc[i][2]; o.w = acc[i][3];
        *(float4*)(outp + (d0 + i) * 64 + e0) = o;
    }
    if (e0 == 0) {
        #pragma unroll
        for (int i = 0; i < 4; ++i) outp[4096 + d0 + i] = acc_ks[i];
    }
}

__global__ __launch_bounds__(256)
void kv_reduce_kernel(const float* __restrict__ KVp, float* __restrict__ KVf)
{
    const int idx = blockIdx.x * 256 + threadIdx.x;
    if (idx < 32 * 4160) {
        float s = 0.f;
        #pragma unroll
        for (int i = 0; i < 16; ++i) s += KVp[(size_t)i * (32 * 4160) + idx];
        KVf[idx] = s;
    }
}

// ---------------------------------------------------------------------------
// O1[n, h*64+e] = Z * sum_d q[n,d]*KV[d,e], Z = 1/(q.ksum + 1e-6); bf16 hi/lo out
// ---------------------------------------------------------------------------
__global__ __launch_bounds__(256)
void attn_apply_kernel(const float* __restrict__ QKV, const float* __restrict__ KVf,
                       ushort* __restrict__ O1hi, ushort* __restrict__ O1lo)
{
    const int bh = blockIdx.x;
    const int b = bh >> 4, h = bh & 15;
    const int n0 = blockIdx.y * 16;
    const int t = threadIdx.x;
    const int r  = t >> 4;
    const int e0 = (t & 15) * 4;

    __shared__ float kvs[64][68];
    __shared__ float qs[16][68];
    __shared__ float ksums[64];

    const float* kvb = KVf + (size_t)bh * 4160;
    for (int i = t; i < 4096; i += 256)
        kvs[i >> 6][i & 63] = kvb[i];
    if (t < 64) ksums[t] = kvb[4096 + t];
    {
        const int rr = t >> 4, cc2 = (t & 15) * 4;
        *(float4*)&qs[rr][cc2] =
            *(const float4*)&QKV[(size_t)(b * N_SEQ + n0 + rr) * 3072 + h * 64 + cc2];
    }
    __syncthreads();

    float4 acc = {0.f, 0.f, 0.f, 0.f};
    float accz = 0.f;
    #pragma unroll
    for (int d = 0; d < 64; ++d) {
        const float qv = qs[r][d];
        const float4 kvv = *(const float4*)&kvs[d][e0];
        acc.x += qv * kvv.x; acc.y += qv * kvv.y;
        acc.z += qv * kvv.z; acc.w += qv * kvv.w;
        accz += qv * ksums[d];
    }
    const float Z = 1.f / (accz + 1e-6f);
    const float vv[4] = {acc.x * Z, acc.y * Z, acc.z * Z, acc.w * Z};
    ushort hv[4], lv[4];
    #pragma unroll
    for (int j = 0; j < 4; ++j) {
        hv[j] = f2bf(vv[j]);
        lv[j] = f2bf(vv[j] - bf2f(hv[j]));
    }
    const size_t off = (size_t)(b * N_SEQ + n0 + r) * C_DIM + h * 64 + e0;
    short4v H = {(short)hv[0], (short)hv[1], (short)hv[2], (short)hv[3]};
    short4v L = {(short)lv[0], (short)lv[1], (short)lv[2], (short)lv[3]};
    *(short4v*)&O1hi[off] = H;
    *(short4v*)&O1lo[off] = L;
}

extern "C" void kernel_launch(void* const* d_in, const int* in_sizes, int n_in,
                              void* d_out, int out_size, void* d_ws, size_t ws_size,
                              hipStream_t stream)
{
    const float* x   = (const float*)d_in[0];
    const float* Wq  = (const float*)d_in[1];
    const float* Wkv = (const float*)d_in[2];
    const float* Wo  = (const float*)d_in[3];
    const float* bo  = (const float*)d_in[4];
    float* out = (float*)d_out;

    float* ws   = (float*)d_ws;
    float* QKV  = ws;                                  // 4096*3072 f32
    float* KVp  = QKV + (size_t)M_ROWS * 3072;         // 16*32*4160
    float* KVf  = KVp + (size_t)16 * 32 * 4160;        // 32*4160
    ushort* xhi = (ushort*)(KVf + 32 * 4160);          // 4096*1024 bf16 each
    ushort* xlo = xhi + (size_t)M_ROWS * 1024;
    ushort* Whi = xlo + (size_t)M_ROWS * 1024;         // 3072*1024 (Wq;Wkv)
    ushort* Wlo = Whi + (size_t)3072 * 1024;
    ushort* Wohi = Wlo + (size_t)3072 * 1024;          // 1024*1024
    ushort* Wolo = Wohi + (size_t)1024 * 1024;
    ushort* O1hi = xhi;                                // alias: x dead after GEMM1
    ushort* O1lo = xlo;

    hipFuncSetAttribute((const void*)gemm1_mfma256_kernel,
                        hipFuncAttributeMaxDynamicSharedMemorySize, 131072);

    // 0. split fp32 -> bf16 hi/lo
    split_all_kernel<<<dim3(4096), 256, 0, stream>>>(
        x, Wq, Wkv, Wo, xhi, xlo, Whi, Wlo, Wohi, Wolo);

    // 1. fused q/k/v projections + elu+1 on q,k (256x192 tiles, full CU fill)
    gemm1_mfma256_kernel<<<dim3(256), 512, 131072, stream>>>(xhi, xlo, Whi, Wlo, QKV);

    // 2-3. KV = K^T V + ksum (split + deterministic reduce)
    kv_partial_kernel<<<dim3(32, 16), 256, 0, stream>>>(QKV, KVp);
    kv_reduce_kernel<<<dim3((32 * 4160 + 255) / 256), 256, 0, stream>>>(KVp, KVf);

    // 4. O1 = Z * (q @ KV), bf16 hi/lo out
    attn_apply_kernel<<<dim3(32, 128), 256, 0, stream>>>(QKV, KVf, O1hi, O1lo);

    // 5. final projection + bias
    gemm2_mfma_kernel<<<dim3(512), 256, 0, stream>>>(O1hi, O1lo, Wohi, Wolo, bo, out);
}

// Round 7
// 148.834 us; speedup vs baseline: 3.2003x; 1.0763x over previous
//
#include <hip/hip_runtime.h>
#include <math.h>

#define C_DIM 1024
#define B_SZ 2
#define N_SEQ 2048
#define M_ROWS (B_SZ * N_SEQ)   // 4096
#define KDIM 1024
#define SLOT_EL 16384           // ushort elements per 32KB gemm1 slot
#define SLOT2_EL 8192           // ushort elements per 16KB gemm2 slot

typedef float  f32x4   __attribute__((ext_vector_type(4)));
typedef short  bf16x8  __attribute__((ext_vector_type(8)));
typedef short  short4v __attribute__((ext_vector_type(4)));
typedef short  short8v __attribute__((ext_vector_type(8)));

__device__ __forceinline__ float elu1(float v) {
    return v > 0.f ? v + 1.f : expf(v);
}

__device__ __forceinline__ ushort f2bf(float f) {
    union { float f; unsigned u; } x; x.f = f;
    unsigned r = (x.u + 0x7fffu + ((x.u >> 16) & 1u)) >> 16;  // RNE
    return (ushort)r;
}
__device__ __forceinline__ float bf2f(ushort b) {
    union { unsigned u; float f; } x; x.u = ((unsigned)b) << 16;
    return x.f;
}

#define VMCNT(n) asm volatile("s_waitcnt vmcnt(" #n ")" ::: "memory")
#define LGKM0    do { asm volatile("s_waitcnt lgkmcnt(0)" ::: "memory"); \
                      __builtin_amdgcn_sched_barrier(0); } while (0)
#define BAR      __builtin_amdgcn_s_barrier()
#define SB0      __builtin_amdgcn_sched_barrier(0)

__device__ __forceinline__ void gl16(const ushort* g, ushort* l) {
    __builtin_amdgcn_global_load_lds(
        (const __attribute__((address_space(1))) unsigned int*)g,
        (__attribute__((address_space(3))) unsigned int*)l,
        16, 0, 0);
}

// ---------------------------------------------------------------------------
// fp32 -> bf16 hi/lo split for all 4 inputs in one launch. 8 elems/thread.
// ---------------------------------------------------------------------------
__global__ __launch_bounds__(256)
void split_all_kernel(const float* __restrict__ x, const float* __restrict__ Wq,
                      const float* __restrict__ Wkv, const float* __restrict__ Wo,
                      ushort* __restrict__ xhi, ushort* __restrict__ xlo,
                      ushort* __restrict__ Whi, ushort* __restrict__ Wlo,
                      ushort* __restrict__ Wohi, ushort* __restrict__ Wolo)
{
    const int i = blockIdx.x * 256 + threadIdx.x;   // 0..1048575
    const float* src; ushort* dh; ushort* dl; int off;
    if (i < 524288)        { src = x;   dh = xhi;  dl = xlo;  off = i; }
    else if (i < 655360)   { src = Wq;  dh = Whi;  dl = Wlo;  off = i - 524288; }
    else if (i < 917504)   { src = Wkv; dh = Whi + (1u << 20); dl = Wlo + (1u << 20); off = i - 655360; }
    else                   { src = Wo;  dh = Wohi; dl = Wolo; off = i - 917504; }

    const float4 a = ((const float4*)src)[off * 2];
    const float4 b = ((const float4*)src)[off * 2 + 1];
    const float v[8] = {a.x, a.y, a.z, a.w, b.x, b.y, b.z, b.w};
    ushort hv[8], lv[8];
    #pragma unroll
    for (int j = 0; j < 8; ++j) {
        hv[j] = f2bf(v[j]);
        lv[j] = f2bf(v[j] - bf2f(hv[j]));
    }
    short8v H = {(short)hv[0],(short)hv[1],(short)hv[2],(short)hv[3],
                 (short)hv[4],(short)hv[5],(short)hv[6],(short)hv[7]};
    short8v L = {(short)lv[0],(short)lv[1],(short)lv[2],(short)lv[3],
                 (short)lv[4],(short)lv[5],(short)lv[6],(short)lv[7]};
    *(short8v*)&dh[(size_t)off * 8] = H;
    *(short8v*)&dl[(size_t)off * 8] = L;
}

// ---------------------------------------------------------------------------
// GEMM1: QKV = [x][Wq;Wkv]^T, 3-term split-bf16, 256x192 tile, BK=32,
// mfma_f32_16x16x32_bf16. 8 waves (2M x 4N), wave tile 128x48. Grid 256
// (full fill). 6-phase rhythm, counted VMCNT(4) at ph1/ph3, 4-slot 128KB.
// ---------------------------------------------------------------------------
__global__ __launch_bounds__(512, 2)
void gemm1_mfma256_kernel(const ushort* __restrict__ Ahi, const ushort* __restrict__ Alo,
                          const ushort* __restrict__ Bhi, const ushort* __restrict__ Blo,
                          float* __restrict__ dst)
{
    extern __shared__ ushort smem[];   // 4 slots x 16384 ushorts (128 KB)

    const int bid = blockIdx.x;
    const int wg  = (bid & 7) * 32 + (bid >> 3);    // bijective: 256 = 8*32
    const int m0  = (wg >> 4) * 256;
    const int n0  = (wg & 15) * 192;

    const int t    = threadIdx.x;
    const int lane = t & 63;
    const int w    = t >> 6;
    const int wr   = w >> 2;       // 0..1
    const int wc   = w & 3;        // 0..3

    const int gch     = (t & 3) ^ ((t >> 3) & 3);
    const size_t rowA  = (size_t)(m0 + (t >> 2)) * KDIM + gch * 8;
    const size_t rowA2 = rowA + (size_t)128 * KDIM;
    const size_t rowB  = (size_t)(n0 + (t >> 2)) * KDIM + gch * 8;
    const int    bclmp = (n0 + (t >> 2) + 128 < 3072) ? (n0 + (t >> 2) + 128) : 3071;
    const size_t rowB2 = (size_t)bclmp * KDIM + gch * 8;
    const int wl      = w * 512;

    const int frow = lane & 15;
    const int cc   = (lane >> 4) ^ ((lane >> 1) & 3);
    const int aoff = (wr * 128 + frow) * 32 + cc * 8;
    const int boff = 8192 + (wc * 48 + frow) * 32 + cc * 8;

    f32x4 acc[8][3];
    #pragma unroll
    for (int mi = 0; mi < 8; ++mi)
        #pragma unroll
        for (int nj = 0; nj < 3; ++nj)
            acc[mi][nj] = (f32x4){0.f, 0.f, 0.f, 0.f};

    #define STAGE_A(src, slotp, koff)                                        \
        do {                                                                 \
            ushort* sl_ = (slotp);                                           \
            gl16((src) + rowA  + (koff), sl_ + wl);                          \
            gl16((src) + rowA2 + (koff), sl_ + 4096 + wl);                   \
        } while (0)
    #define STAGE_B(src, slotp, koff)                                        \
        do {                                                                 \
            ushort* sl_ = (slotp);                                           \
            gl16((src) + rowB  + (koff), sl_ + 8192 + wl);                   \
            gl16((src) + rowB2 + (koff), sl_ + 12288 + wl);                  \
        } while (0)

    STAGE_A(Ahi, smem, 0);
    STAGE_B(Bhi, smem, 0);
    STAGE_A(Alo, smem + SLOT_EL, 0);
    STAGE_B(Blo, smem + SLOT_EL, 0);

    #pragma unroll 1
    for (int kt = 0; kt < 32; ++kt) {
        ushort* sh = smem + ((kt & 1) << 1) * SLOT_EL;
        ushort* sl = sh + SLOT_EL;
        ushort* nh = smem + ((2 * kt + 2) & 3) * SLOT_EL;
        ushort* nl = smem + ((2 * kt + 3) & 3) * SLOT_EL;
        const int kn = (kt + 1) * 32;

        bf16x8 ah[8], bh[3], bl[3], al[8];

        // ---- ph1
        VMCNT(4);
        BAR; SB0;
        #pragma unroll
        for (int mi = 0; mi < 4; ++mi)
            ah[mi] = *(const bf16x8*)(sh + aoff + mi * 512);
        #pragma unroll
        for (int nj = 0; nj < 3; ++nj)
            bh[nj] = *(const bf16x8*)(sh + boff + nj * 512);
        if (kt < 31) STAGE_A(Ahi, nh, kn);
        LGKM0;
        __builtin_amdgcn_s_setprio(1);
        #pragma unroll
        for (int mi = 0; mi < 4; ++mi)
            #pragma unroll
            for (int nj = 0; nj < 3; ++nj)
                acc[mi][nj] = __builtin_amdgcn_mfma_f32_16x16x32_bf16(
                    ah[mi], bh[nj], acc[mi][nj], 0, 0, 0);
        __builtin_amdgcn_s_setprio(0);
        BAR;

        // ---- ph2
        #pragma unroll
        for (int mi = 4; mi < 8; ++mi)
            ah[mi] = *(const bf16x8*)(sh + aoff + mi * 512);
        if (kt < 31) STAGE_B(Bhi, nh, kn);
        BAR;
        LGKM0;
        __builtin_amdgcn_s_setprio(1);
        #pragma unroll
        for (int mi = 4; mi < 8; ++mi)
            #pragma unroll
            for (int nj = 0; nj < 3; ++nj)
                acc[mi][nj] = __builtin_amdgcn_mfma_f32_16x16x32_bf16(
                    ah[mi], bh[nj], acc[mi][nj], 0, 0, 0);
        __builtin_amdgcn_s_setprio(0);
        BAR;

        // ---- ph3
        if (kt < 31) { VMCNT(4); } else { VMCNT(0); }
        BAR; SB0;
        #pragma unroll
        for (int nj = 0; nj < 3; ++nj)
            bl[nj] = *(const bf16x8*)(sl + boff + nj * 512);
        if (kt < 31) STAGE_A(Alo, nl, kn);
        LGKM0;
        __builtin_amdgcn_s_setprio(1);
        #pragma unroll
        for (int mi = 0; mi < 4; ++mi)
            #pragma unroll
            for (int nj = 0; nj < 3; ++nj)
                acc[mi][nj] = __builtin_amdgcn_mfma_f32_16x16x32_bf16(
                    ah[mi], bl[nj], acc[mi][nj], 0, 0, 0);
        __builtin_amdgcn_s_setprio(0);
        BAR;

        // ---- ph4
        #pragma unroll
        for (int mi = 0; mi < 4; ++mi)
            al[mi] = *(const bf16x8*)(sl + aoff + mi * 512);
        if (kt < 31) STAGE_B(Blo, nl, kn);
        BAR;
        LGKM0;
        __builtin_amdgcn_s_setprio(1);
        #pragma unroll
        for (int mi = 4; mi < 8; ++mi)
            #pragma unroll
            for (int nj = 0; nj < 3; ++nj)
                acc[mi][nj] = __builtin_amdgcn_mfma_f32_16x16x32_bf16(
                    ah[mi], bl[nj], acc[mi][nj], 0, 0, 0);
        __builtin_amdgcn_s_setprio(0);
        BAR;

        // ---- ph5
        #pragma unroll
        for (int mi = 4; mi < 8; ++mi)
            al[mi] = *(const bf16x8*)(sl + aoff + mi * 512);
        BAR;
        LGKM0;
        __builtin_amdgcn_s_setprio(1);
        #pragma unroll
        for (int mi = 0; mi < 4; ++mi)
            #pragma unroll
            for (int nj = 0; nj < 3; ++nj)
                acc[mi][nj] = __builtin_amdgcn_mfma_f32_16x16x32_bf16(
                    al[mi], bh[nj], acc[mi][nj], 0, 0, 0);
        __builtin_amdgcn_s_setprio(0);
        BAR;

        // ---- ph6
        __builtin_amdgcn_s_setprio(1);
        #pragma unroll
        for (int mi = 4; mi < 8; ++mi)
            #pragma unroll
            for (int nj = 0; nj < 3; ++nj)
                acc[mi][nj] = __builtin_amdgcn_mfma_f32_16x16x32_bf16(
                    al[mi], bh[nj], acc[mi][nj], 0, 0, 0);
        __builtin_amdgcn_s_setprio(0);
        BAR;
    }
    #undef STAGE_A
    #undef STAGE_B

    const int erow  = m0 + wr * 128 + (lane >> 4) * 4;
    const int ecol0 = n0 + wc * 48 + frow;
    #pragma unroll
    for (int mi = 0; mi < 8; ++mi) {
        #pragma unroll
        for (int j = 0; j < 4; ++j) {
            const int row = erow + mi * 16 + j;
            #pragma unroll
            for (int nj = 0; nj < 3; ++nj) {
                const int col = ecol0 + nj * 16;
                float v = acc[mi][nj][j];
                if (col < 2048) v = elu1(v);
                dst[(size_t)row * 3072 + col] = v;
            }
        }
    }
}

// ---------------------------------------------------------------------------
// GEMM2: out = O1 @ Wo^T + bo. 128x128 tile, BK=32, 4 waves (2x2, 64x64/wave),
// 3-phase/kt rhythm (hh/hl/lh, 16 MFMA each), 4-slot 64KB LDS, counted
// vmcnt(4)/vmcnt(2). Grid 256 = 32m x 8n -> full fill.
// ---------------------------------------------------------------------------
__global__ __launch_bounds__(256, 2)
void gemm2_mfma_kernel(const ushort* __restrict__ Ahi, const ushort* __restrict__ Alo,
                       const ushort* __restrict__ Bhi, const ushort* __restrict__ Blo,
                       const float* __restrict__ bias, float* __restrict__ dst)
{
    __shared__ ushort smem[4 * SLOT2_EL];   // 64 KB

    const int bid = blockIdx.x;
    const int wg  = (bid & 7) * 32 + (bid >> 3);    // bijective: 256 = 8*32
    const int m0  = (wg >> 3) * 128;                // 32 m-tiles
    const int n0  = (wg & 7) * 128;                 // 8 n-tiles

    const int t    = threadIdx.x;
    const int lane = t & 63;
    const int w    = t >> 6;      // 0..3
    const int wr   = w >> 1;      // 0..1
    const int wc   = w & 1;       // 0..1

    const int gch     = (t & 3) ^ ((t >> 3) & 3);
    const size_t rowA = (size_t)(m0 + (t >> 2)) * KDIM + gch * 8;
    const size_t rowB = (size_t)(n0 + (t >> 2)) * KDIM + gch * 8;
    const int wl      = w * 512;

    const int frow = lane & 15;
    const int cc   = (lane >> 4) ^ ((lane >> 1) & 3);
    const int aoff = (wr * 64 + frow) * 32 + cc * 8;
    const int boff = 4096 + (wc * 64 + frow) * 32 + cc * 8;

    f32x4 acc[4][4];
    #pragma unroll
    for (int mi = 0; mi < 4; ++mi)
        #pragma unroll
        for (int nj = 0; nj < 4; ++nj)
            acc[mi][nj] = (f32x4){0.f, 0.f, 0.f, 0.f};

    #define G2A(src, slotp, koff)                                            \
        do {                                                                 \
            ushort* p_ = (slotp);                                            \
            gl16((src) + rowA + (koff),         p_ + wl);                    \
            gl16((src) + rowA + 65536 + (koff), p_ + 2048 + wl);             \
        } while (0)
    #define G2B(src, slotp, koff)                                            \
        do {                                                                 \
            ushort* p_ = (slotp);                                            \
            gl16((src) + rowB + (koff),         p_ + 4096 + wl);             \
            gl16((src) + rowB + 65536 + (koff), p_ + 6144 + wl);             \
        } while (0)

    G2A(Ahi, smem, 0);
    G2B(Bhi, smem, 0);
    G2A(Alo, smem + SLOT2_EL, 0);
    G2B(Blo, smem + SLOT2_EL, 0);

    #pragma unroll 1
    for (int kt = 0; kt < 32; ++kt) {
        ushort* sh = smem + ((kt & 1) << 1) * SLOT2_EL;
        ushort* sl = sh + SLOT2_EL;
        ushort* nh = smem + ((2 * kt + 2) & 3) * SLOT2_EL;
        ushort* nl = smem + ((2 * kt + 3) & 3) * SLOT2_EL;
        const int kn = (kt + 1) * 32;

        bf16x8 ah[4], bh[4], bl[4], al[4];

        // ---- ph1: hh
        VMCNT(4);
        BAR; SB0;
        #pragma unroll
        for (int mi = 0; mi < 4; ++mi)
            ah[mi] = *(const bf16x8*)(sh + aoff + mi * 512);
        #pragma unroll
        for (int nj = 0; nj < 4; ++nj)
            bh[nj] = *(const bf16x8*)(sh + boff + nj * 512);
        if (kt < 31) G2A(Ahi, nh, kn);
        LGKM0;
        __builtin_amdgcn_s_setprio(1);
        #pragma unroll
        for (int mi = 0; mi < 4; ++mi)
            #pragma unroll
            for (int nj = 0; nj < 4; ++nj)
                acc[mi][nj] = __builtin_amdgcn_mfma_f32_16x16x32_bf16(
                    ah[mi], bh[nj], acc[mi][nj], 0, 0, 0);
        __builtin_amdgcn_s_setprio(0);
        BAR;

        // ---- ph2: hl  (ah x bl)
        if (kt < 31) { VMCNT(2); } else { VMCNT(0); }
        BAR; SB0;
        #pragma unroll
        for (int nj = 0; nj < 4; ++nj)
            bl[nj] = *(const bf16x8*)(sl + boff + nj * 512);
        if (kt < 31) G2B(Bhi, nh, kn);
        LGKM0;
        __builtin_amdgcn_s_setprio(1);
        #pragma unroll
        for (int mi = 0; mi < 4; ++mi)
            #pragma unroll
            for (int nj = 0; nj < 4; ++nj)
                acc[mi][nj] = __builtin_amdgcn_mfma_f32_16x16x32_bf16(
                    ah[mi], bl[nj], acc[mi][nj], 0, 0, 0);
        __builtin_amdgcn_s_setprio(0);
        BAR;

        // ---- ph3: lh  (al x bh)
        #pragma unroll
        for (int mi = 0; mi < 4; ++mi)
            al[mi] = *(const bf16x8*)(sl + aoff + mi * 512);
        if (kt < 31) { G2A(Alo, nl, kn); G2B(Blo, nl, kn); }
        BAR;
        LGKM0;
        __builtin_amdgcn_s_setprio(1);
        #pragma unroll
        for (int mi = 0; mi < 4; ++mi)
            #pragma unroll
            for (int nj = 0; nj < 4; ++nj)
                acc[mi][nj] = __builtin_amdgcn_mfma_f32_16x16x32_bf16(
                    al[mi], bh[nj], acc[mi][nj], 0, 0, 0);
        __builtin_amdgcn_s_setprio(0);
        BAR;
    }
    #undef G2A
    #undef G2B

    const int erow  = m0 + wr * 64 + (lane >> 4) * 4;
    const int ecol0 = n0 + wc * 64 + frow;
    #pragma unroll
    for (int mi = 0; mi < 4; ++mi) {
        #pragma unroll
        for (int j = 0; j < 4; ++j) {
            const int row = erow + mi * 16 + j;
            #pragma unroll
            for (int nj = 0; nj < 4; ++nj) {
                const int col = ecol0 + nj * 16;
                dst[(size_t)row * 1024 + col] = acc[mi][nj][j] + bias[col];
            }
        }
    }
}

// ---------------------------------------------------------------------------
// Partial KV = K_feat^T V and ksum, per (b,h), 8-way N split (256 rows each).
// 256 threads = 4 rowsets x (8d x 8e). float4 staging, prefetched. In-block
// rowset merge via LDS -> 8 partials. Grid (32, 8) = 256 blocks, full fill.
// ---------------------------------------------------------------------------
__global__ __launch_bounds__(256)
void kv_partial_kernel(const float* __restrict__ QKV, float* __restrict__ KVp)
{
    const int bh = blockIdx.x;   // 0..31
    const int s  = blockIdx.y;   // 0..7
    const int b  = bh >> 4;
    const int h  = bh & 15;
    const int t  = threadIdx.x;

    __shared__ float ks[16][64];
    __shared__ float vs[16][64];
    __shared__ float red[4160];

    // staging mapping: thread -> (row t>>4, col quad t&15)
    const int srow = t >> 4;
    const int scol = (t & 15) * 4;
    const size_t gk = (size_t)(b * N_SEQ + s * 256) * 3072 + 1024 + h * 64 + scol;
    const size_t gv = gk + 1024;

    // compute mapping: rowset x (8d x 8e)
    const int rs = t >> 6;
    const int dg = (t >> 3) & 7;
    const int eg = t & 7;
    const int d0 = dg * 8;
    const int e0 = eg * 8;

    float acc[8][8];
    #pragma unroll
    for (int i = 0; i < 8; ++i)
        #pragma unroll
        for (int j = 0; j < 8; ++j) acc[i][j] = 0.f;
    float aks[8] = {0.f, 0.f, 0.f, 0.f, 0.f, 0.f, 0.f, 0.f};

    float4 kr = *(const float4*)&QKV[gk + (size_t)srow * 3072];
    float4 vr = *(const float4*)&QKV[gv + (size_t)srow * 3072];

    for (int it = 0; it < 16; ++it) {
        __syncthreads();
        *(float4*)&ks[srow][scol] = kr;
        *(float4*)&vs[srow][scol] = vr;
        __syncthreads();
        if (it < 15) {
            kr = *(const float4*)&QKV[gk + (size_t)((it + 1) * 16 + srow) * 3072];
            vr = *(const float4*)&QKV[gv + (size_t)((it + 1) * 16 + srow) * 3072];
        }
        #pragma unroll
        for (int rr = 0; rr < 4; ++rr) {
            const int r = rs * 4 + rr;
            const float4 ka = *(const float4*)&ks[r][d0];
            const float4 kb = *(const float4*)&ks[r][d0 + 4];
            const float4 va = *(const float4*)&vs[r][e0];
            const float4 vb = *(const float4*)&vs[r][e0 + 4];
            const float k8[8] = {ka.x, ka.y, ka.z, ka.w, kb.x, kb.y, kb.z, kb.w};
            const float v8[8] = {va.x, va.y, va.z, va.w, vb.x, vb.y, vb.z, vb.w};
            #pragma unroll
            for (int i = 0; i < 8; ++i)
                #pragma unroll
                for (int j = 0; j < 8; ++j)
                    acc[i][j] += k8[i] * v8[j];
            if (eg == 0) {
                #pragma unroll
                for (int i = 0; i < 8; ++i) aks[i] += k8[i];
            }
        }
    }

    // merge rowsets 1..3 into rowset 0
    #pragma unroll 1
    for (int step = 1; step < 4; ++step) {
        __syncthreads();
        if (rs == step) {
            #pragma unroll
            for (int i = 0; i < 8; ++i)
                #pragma unroll
                for (int j = 0; j < 8; ++j)
                    red[(d0 + i) * 64 + e0 + j] = acc[i][j];
            if (eg == 0) {
                #pragma unroll
                for (int i = 0; i < 8; ++i) red[4096 + d0 + i] = aks[i];
            }
        }
        __syncthreads();
        if (rs == 0) {
            #pragma unroll
            for (int i = 0; i < 8; ++i)
                #pragma unroll
                for (int j = 0; j < 8; ++j)
                    acc[i][j] += red[(d0 + i) * 64 + e0 + j];
            if (eg == 0) {
                #pragma unroll
                for (int i = 0; i < 8; ++i) aks[i] += red[4096 + d0 + i];
            }
        }
    }

    if (rs == 0) {
        float* outp = KVp + ((size_t)s * 32 + bh) * 4160;
        #pragma unroll
        for (int i = 0; i < 8; ++i) {
            float4 o0 = {acc[i][0], acc[i][1], acc[i][2], acc[i][3]};
            float4 o1 = {acc[i][4], acc[i][5], acc[i][6], acc[i][7]};
            *(float4*)(outp + (d0 + i) * 64 + e0)     = o0;
            *(float4*)(outp + (d0 + i) * 64 + e0 + 4) = o1;
        }
        if (eg == 0) {
            #pragma unroll
            for (int i = 0; i < 8; ++i) outp[4096 + d0 + i] = aks[i];
        }
    }
}

// Deterministic reduce of the 8 partials.
__global__ __launch_bounds__(256)
void kv_reduce_kernel(const float* __restrict__ KVp, float* __restrict__ KVf)
{
    const int idx = blockIdx.x * 256 + threadIdx.x;
    if (idx < 32 * 4160) {
        float s = 0.f;
        #pragma unroll
        for (int i = 0; i < 8; ++i) s += KVp[(size_t)i * (32 * 4160) + idx];
        KVf[idx] = s;
    }
}

// ---------------------------------------------------------------------------
// O1[n, h*64+e] = Z * sum_d q[n,d]*KV[d,e], Z = 1/(q.ksum + 1e-6); bf16 hi/lo out
// ---------------------------------------------------------------------------
__global__ __launch_bounds__(256)
void attn_apply_kernel(const float* __restrict__ QKV, const float* __restrict__ KVf,
                       ushort* __restrict__ O1hi, ushort* __restrict__ O1lo)
{
    const int bh = blockIdx.x;
    const int b = bh >> 4, h = bh & 15;
    const int n0 = blockIdx.y * 16;
    const int t = threadIdx.x;
    const int r  = t >> 4;
    const int e0 = (t & 15) * 4;

    __shared__ float kvs[64][68];
    __shared__ float qs[16][68];
    __shared__ float ksums[64];

    const float* kvb = KVf + (size_t)bh * 4160;
    for (int i = t; i < 4096; i += 256)
        kvs[i >> 6][i & 63] = kvb[i];
    if (t < 64) ksums[t] = kvb[4096 + t];
    {
        const int rr = t >> 4, cc2 = (t & 15) * 4;
        *(float4*)&qs[rr][cc2] =
            *(const float4*)&QKV[(size_t)(b * N_SEQ + n0 + rr) * 3072 + h * 64 + cc2];
    }
    __syncthreads();

    float4 acc = {0.f, 0.f, 0.f, 0.f};
    float accz = 0.f;
    #pragma unroll
    for (int d = 0; d < 64; ++d) {
        const float qv = qs[r][d];
        const float4 kvv = *(const float4*)&kvs[d][e0];
        acc.x += qv * kvv.x; acc.y += qv * kvv.y;
        acc.z += qv * kvv.z; acc.w += qv * kvv.w;
        accz += qv * ksums[d];
    }
    const float Z = 1.f / (accz + 1e-6f);
    const float vv[4] = {acc.x * Z, acc.y * Z, acc.z * Z, acc.w * Z};
    ushort hv[4], lv[4];
    #pragma unroll
    for (int j = 0; j < 4; ++j) {
        hv[j] = f2bf(vv[j]);
        lv[j] = f2bf(vv[j] - bf2f(hv[j]));
    }
    const size_t off = (size_t)(b * N_SEQ + n0 + r) * C_DIM + h * 64 + e0;
    short4v H = {(short)hv[0], (short)hv[1], (short)hv[2], (short)hv[3]};
    short4v L = {(short)lv[0], (short)lv[1], (short)lv[2], (short)lv[3]};
    *(short4v*)&O1hi[off] = H;
    *(short4v*)&O1lo[off] = L;
}

extern "C" void kernel_launch(void* const* d_in, const int* in_sizes, int n_in,
                              void* d_out, int out_size, void* d_ws, size_t ws_size,
                              hipStream_t stream)
{
    const float* x   = (const float*)d_in[0];
    const float* Wq  = (const float*)d_in[1];
    const float* Wkv = (const float*)d_in[2];
    const float* Wo  = (const float*)d_in[3];
    const float* bo  = (const float*)d_in[4];
    float* out = (float*)d_out;

    float* ws   = (float*)d_ws;
    float* QKV  = ws;                                  // 4096*3072 f32
    float* KVp  = QKV + (size_t)M_ROWS * 3072;         // 8*32*4160
    float* KVf  = KVp + (size_t)8 * 32 * 4160;         // 32*4160
    ushort* xhi = (ushort*)(KVf + 32 * 4160);          // 4096*1024 bf16 each
    ushort* xlo = xhi + (size_t)M_ROWS * 1024;
    ushort* Whi = xlo + (size_t)M_ROWS * 1024;         // 3072*1024 (Wq;Wkv)
    ushort* Wlo = Whi + (size_t)3072 * 1024;
    ushort* Wohi = Wlo + (size_t)3072 * 1024;          // 1024*1024
    ushort* Wolo = Wohi + (size_t)1024 * 1024;
    ushort* O1hi = xhi;                                // alias: x dead after GEMM1
    ushort* O1lo = xlo;

    hipFuncSetAttribute((const void*)gemm1_mfma256_kernel,
                        hipFuncAttributeMaxDynamicSharedMemorySize, 131072);

    // 0. split fp32 -> bf16 hi/lo
    split_all_kernel<<<dim3(4096), 256, 0, stream>>>(
        x, Wq, Wkv, Wo, xhi, xlo, Whi, Wlo, Wohi, Wolo);

    // 1. fused q/k/v projections + elu+1 on q,k
    gemm1_mfma256_kernel<<<dim3(256), 512, 131072, stream>>>(xhi, xlo, Whi, Wlo, QKV);

    // 2-3. KV = K^T V + ksum (8-way split + deterministic reduce)
    kv_partial_kernel<<<dim3(32, 8), 256, 0, stream>>>(QKV, KVp);
    kv_reduce_kernel<<<dim3((32 * 4160 + 255) / 256), 256, 0, stream>>>(KVp, KVf);

    // 4. O1 = Z * (q @ KV), bf16 hi/lo out
    attn_apply_kernel<<<dim3(32, 128), 256, 0, stream>>>(QKV, KVf, O1hi, O1lo);

    // 5. final projection + bias
    gemm2_mfma_kernel<<<dim3(256), 256, 0, stream>>>(O1hi, O1lo, Wohi, Wolo, bo, out);
}